// Round 9
// baseline (546.703 us; speedup 1.0000x reference)
//
#include <hip/hip_runtime.h>
#include <hip/hip_bf16.h>
#include <math.h>

// ---------------------------------------------------------------------------
// MLA forward, bf16 MFMA.
// r9 = r8 with the flags-lifetime fix: the merge-flag memset is issued AFTER
// rope_vtrans (C1's last reader) and immediately before attn_split. r8's bug:
// flags live at ws+33MB inside C1 [25,37MB); the top-of-stream memset was
// clobbered by gemm1's C1 writes -> merges never fired -> absmax 0.887.
// (1) GEMMs BK=64 (halved vmcnt0+barrier drains; Vs-pattern XOR swizzle),
// (2) attn_merge fused into attn_split via device-scope atomic flag.
// ROUND-4 LESSON: never force min-waves launch_bounds (VGPR cap -> spill).
// ROUND-5 LESSON: extra split-K ways cost ~16MB partial traffic per way.
// ROUND-6/8 LESSON: audit overlay LIFETIMES against the full stream schedule.
// B=2 S=2048 H=2048 nh=16 hd=128 rd=64 L=256
// ---------------------------------------------------------------------------

typedef __attribute__((ext_vector_type(8))) short bf16x8;
typedef __attribute__((ext_vector_type(4))) float f32x4;
typedef unsigned int u32;

#define MFMA16(a, b, c) __builtin_amdgcn_mfma_f32_16x16x32_bf16(a, b, c, 0, 0, 0)

__device__ __forceinline__ short f2bs(float f) {
  __hip_bfloat16 h = __float2bfloat16(f);
  return *reinterpret_cast<short*>(&h);
}
__device__ __forceinline__ float bs2f(short s) {
  union { unsigned int u; float f; } v;
  v.u = ((unsigned int)(unsigned short)s) << 16;
  return v.f;
}
__device__ __forceinline__ u32 fbits(float f) {
  union { float f; u32 u; } v; v.f = f; return v.u;
}

__device__ __forceinline__ void async16(const void* g, void* l) {
  __builtin_amdgcn_global_load_lds(
      (const __attribute__((address_space(1))) u32*)(unsigned long long)g,
      (__attribute__((address_space(3))) u32*)(unsigned int)(unsigned long long)l,
      16, 0, 0);
}
__device__ __forceinline__ void wait_vm0() {
  __builtin_amdgcn_s_waitcnt(0x0f70);  // vmcnt(0) only
}

// ---------------- fused prep: cast hs + all weight transposes --------------
__device__ __forceinline__ void wtrans_tile(const float* __restrict__ W,
                                            short* __restrict__ Wt, int K, int N,
                                            int bx, int by, int tid) {
  __shared__ float t[32][33];
  int k0 = by * 32, n0 = bx * 32;
#pragma unroll
  for (int i = 0; i < 4; ++i) {
    int idx = tid + i * 256;
    int r = idx >> 5, c = idx & 31;
    t[r][c] = W[(size_t)(k0 + r) * N + n0 + c];
  }
  __syncthreads();
#pragma unroll
  for (int i = 0; i < 4; ++i) {
    int idx = tid + i * 256;
    int r = idx >> 5, c = idx & 31;
    Wt[(size_t)(n0 + r) * K + k0 + c] = f2bs(t[c][r]);
  }
}

__global__ __launch_bounds__(256) void prep_all(
    const float* __restrict__ hs, const float* __restrict__ Wkvd,
    const float* __restrict__ Wqd, const float* __restrict__ Wku,
    const float* __restrict__ Wqu, const float* __restrict__ Wvu,
    const float* __restrict__ Wrk, const float* __restrict__ Wrq,
    const float* __restrict__ Wo, short* __restrict__ hs_b,
    short* __restrict__ W1t, short* __restrict__ W2t,
    short* __restrict__ W3t, short* __restrict__ Wo_t) {
  const int b = blockIdx.x, tid = threadIdx.x;
  if (b < 8192) {
    int i = (b * 256 + tid) * 4;
    float4 v = *(const float4*)(hs + i);
    short4 o;
    o.x = f2bs(v.x); o.y = f2bs(v.y); o.z = f2bs(v.z); o.w = f2bs(v.w);
    *(short4*)(hs_b + i) = o;
  } else if (b < 8704) {
    int l = b - 8192; wtrans_tile(Wkvd, W1t, 2048, 256, l & 7, l >> 3, tid);
  } else if (b < 9216) {
    int l = b - 8704; wtrans_tile(Wqd, W1t + 256 * 2048, 2048, 256, l & 7, l >> 3, tid);
  } else if (b < 11264) {
    int l = b - 9216; wtrans_tile(Wrk, W1t + 512 * 2048, 2048, 1024, l & 31, l >> 5, tid);
  } else if (b < 11520) {
    int l = b - 11264; wtrans_tile(Wku, W2t, 256, 1024, l & 31, l >> 5, tid);
  } else if (b < 12032) {
    int l = b - 11520; wtrans_tile(Wvu, W2t + 1024 * 256, 256, 2048, l & 63, l >> 6, tid);
  } else if (b < 12288) {
    int l = b - 12032; wtrans_tile(Wqu, W3t, 256, 1024, l & 31, l >> 5, tid);
  } else if (b < 12544) {
    int l = b - 12288; wtrans_tile(Wrq, W3t + 1024 * 256, 256, 1024, l & 31, l >> 5, tid);
  } else {
    int l = b - 12544; wtrans_tile(Wo, Wo_t, 2048, 2048, l & 63, l >> 6, tid);
  }
}

// ---------------- bf16 MFMA GEMM, BK=64, swizzled staging: C = A @ Bt^T ----
// Staging: LDS[r][c] = global[r][c ^ (r&7)] (chunk=8 shorts); read slot
// (s*4+quad) ^ (l15&7) recovers global chunk s*4+quad (row&7 == l15&7).
__device__ __forceinline__ void cstore(float v, float* p) { *p = v; }
__device__ __forceinline__ void cstore(float v, short* p) { *p = f2bs(v); }

template <typename CT>
__global__ __launch_bounds__(256) void gemm_bt(const short* __restrict__ A, int lda,
                                               const short* __restrict__ Bt, int ldb,
                                               CT* __restrict__ C, int ldc, int K) {
  __shared__ short As[128 * 64];
  __shared__ short Bs[128 * 64];
  const int tid = threadIdx.x;
  const int wave = tid >> 6, lane = tid & 63;
  const int quad = lane >> 4, l15 = lane & 15;
  const int wm = wave & 1, wn = wave >> 1;
  const int row0 = blockIdx.y * 128, col0 = blockIdx.x * 128;
  const int sr = tid >> 3;                    // staging row 0..31 (+i*32)
  const int sc = ((tid & 7) ^ (sr & 7)) * 8;  // inverse-swizzled global chunk
  const short* Ag = A + (size_t)(row0 + sr) * lda + sc;
  const short* Bg = Bt + (size_t)(col0 + sr) * ldb + sc;
  const int rk = l15 & 7;                     // read-side XOR key (row&7)

  f32x4 acc[4][4];
#pragma unroll
  for (int i = 0; i < 4; ++i)
#pragma unroll
    for (int j = 0; j < 4; ++j) acc[i][j] = {0.f, 0.f, 0.f, 0.f};

  for (int k0 = 0; k0 < K; k0 += 64) {
    __syncthreads();
#pragma unroll
    for (int i = 0; i < 4; ++i) {
      async16(Ag + (size_t)(i * 32) * lda + k0, &As[i * 2048 + tid * 8]);
      async16(Bg + (size_t)(i * 32) * ldb + k0, &Bs[i * 2048 + tid * 8]);
    }
    wait_vm0();
    __syncthreads();
#pragma unroll
    for (int s = 0; s < 2; ++s) {
      bf16x8 af[4], bfr[4];
#pragma unroll
      for (int i = 0; i < 4; ++i) {
        af[i]  = *(const bf16x8*)&As[(wm * 64 + i * 16 + l15) * 64 +
                                     ((s * 4 + quad) ^ rk) * 8];
        bfr[i] = *(const bf16x8*)&Bs[(wn * 64 + i * 16 + l15) * 64 +
                                     ((s * 4 + quad) ^ rk) * 8];
      }
#pragma unroll
      for (int i = 0; i < 4; ++i)
#pragma unroll
        for (int j = 0; j < 4; ++j)
          acc[i][j] = MFMA16(af[i], bfr[j], acc[i][j]);
    }
  }
#pragma unroll
  for (int i = 0; i < 4; ++i)
#pragma unroll
    for (int j = 0; j < 4; ++j)
#pragma unroll
      for (int r = 0; r < 4; ++r) {
        int row = row0 + wm * 64 + i * 16 + quad * 4 + r;
        int col = col0 + wn * 64 + j * 16 + l15;
        cstore(acc[i][j][r], &C[(size_t)row * ldc + col]);
      }
}

// ---- fused gemm2+gemm3, BK=64: A=C1(/+256), B rows contiguous W2t|W3t -----
// REQUIRES: W3t == W2t + 3072*256 (enforced in kernel_launch layout).
__global__ __launch_bounds__(256) void gemm23(const short* __restrict__ C1,
                                              const short* __restrict__ W2t,
                                              short* __restrict__ C2,
                                              short* __restrict__ C3) {
  __shared__ short As[128 * 64];
  __shared__ short Bs[128 * 64];
  const int tid = threadIdx.x;
  const int wave = tid >> 6, lane = tid & 63;
  const int quad = lane >> 4, l15 = lane & 15;
  const int wm = wave & 1, wn = wave >> 1;
  const int bx = blockIdx.x;
  const bool isC2 = bx < 24;
  short* C = isC2 ? C2 : C3;
  const int ldc = isC2 ? 3072 : 2048;
  const int colbase = isC2 ? bx * 128 : (bx - 24) * 128;
  const short* A = isC2 ? C1 : C1 + 256;  // kv_d vs q_d columns of C1
  const int row0 = blockIdx.y * 128;
  const int sr = tid >> 3;
  const int sc = ((tid & 7) ^ (sr & 7)) * 8;
  const short* Ag = A + (size_t)(row0 + sr) * 1536 + sc;
  const short* Bg = W2t + (size_t)(bx * 128 + sr) * 256 + sc;  // W3t contiguous
  const int rk = l15 & 7;

  f32x4 acc[4][4];
#pragma unroll
  for (int i = 0; i < 4; ++i)
#pragma unroll
    for (int j = 0; j < 4; ++j) acc[i][j] = {0.f, 0.f, 0.f, 0.f};

  for (int k0 = 0; k0 < 256; k0 += 64) {
    __syncthreads();
#pragma unroll
    for (int i = 0; i < 4; ++i) {
      async16(Ag + (size_t)(i * 32) * 1536 + k0, &As[i * 2048 + tid * 8]);
      async16(Bg + (size_t)(i * 32) * 256 + k0, &Bs[i * 2048 + tid * 8]);
    }
    wait_vm0();
    __syncthreads();
#pragma unroll
    for (int s = 0; s < 2; ++s) {
      bf16x8 af[4], bfr[4];
#pragma unroll
      for (int i = 0; i < 4; ++i) {
        af[i]  = *(const bf16x8*)&As[(wm * 64 + i * 16 + l15) * 64 +
                                     ((s * 4 + quad) ^ rk) * 8];
        bfr[i] = *(const bf16x8*)&Bs[(wn * 64 + i * 16 + l15) * 64 +
                                     ((s * 4 + quad) ^ rk) * 8];
      }
#pragma unroll
      for (int i = 0; i < 4; ++i)
#pragma unroll
        for (int j = 0; j < 4; ++j)
          acc[i][j] = MFMA16(af[i], bfr[j], acc[i][j]);
    }
  }
#pragma unroll
  for (int i = 0; i < 4; ++i)
#pragma unroll
    for (int j = 0; j < 4; ++j)
#pragma unroll
      for (int r = 0; r < 4; ++r) {
        int row = row0 + wm * 64 + i * 16 + quad * 4 + r;
        int col = colbase + wn * 64 + j * 16 + l15;
        cstore(acc[i][j][r], &C[(size_t)row * ldc + col]);
      }
}

// ---------------- fused RoPE-pack + V-transpose ----------------------------
__global__ __launch_bounds__(256) void rope_vtrans(
    const short* __restrict__ c3, const short* __restrict__ c2,
    const short* __restrict__ c1, short* __restrict__ qf,
    short* __restrict__ kf, short* __restrict__ vt) {
  if (blockIdx.x < 32768) {
    const float QSCALE = 0.08838834764831845f * 1.4426950408889634f;
    int idx = blockIdx.x * 256 + threadIdx.x;
    int m = idx >> 11;
    int col = idx & 2047;
    int h = col >> 7;
    int j = col & 127;
    int b = m >> 11, s = m & 2047;
    float oq, ok;
    if (j < 64) {
      oq = bs2f(c3[(size_t)m * 2048 + h * 64 + j]);
      ok = bs2f(c2[(size_t)m * 3072 + h * 64 + j]);
    } else {
      int jr = j - 64;
      int f = jr & 31;
      float ang = (float)s * __expf(-0.2878231366242557f * (float)f);
      float c = __cosf(ang), sn = __sinf(ang);
      size_t qb = (size_t)m * 2048 + 1024 + h * 64;
      size_t kb = (size_t)m * 1536 + 512 + h * 64;
      float xq = bs2f(c3[qb + jr]), xk = bs2f(c1[kb + jr]);
      float rq, rk;
      if (jr < 32) { rq = -bs2f(c3[qb + jr + 32]); rk = -bs2f(c1[kb + jr + 32]); }
      else         { rq =  bs2f(c3[qb + jr - 32]); rk =  bs2f(c1[kb + jr - 32]); }
      oq = fmaf(xq, c, rq * sn);
      ok = fmaf(xk, c, rk * sn);
    }
    size_t dst = (((size_t)b * 16 + h) * 2048 + s) * 128 + j;
    qf[dst] = f2bs(oq * QSCALE);
    kf[dst] = f2bs(ok);
  } else {
    __shared__ short t[64][72];
    const int l = blockIdx.x - 32768;  // 0..2047
    const int bh = ((l & 7) << 2) | ((l >> 3) & 3);  // lid%8 == bh>>2 (XCD)
    const int s0 = ((l >> 5) & 31) * 64;
    const int d0 = ((l >> 10) & 1) * 64;
    const int b = bh >> 4, h = bh & 15;
#pragma unroll
    for (int i = 0; i < 16; ++i) {
      int idx = threadIdx.x + i * 256;
      int r = idx >> 6, c = idx & 63;
      t[r][c] = c2[(size_t)(b * 2048 + s0 + r) * 3072 + 1024 + h * 128 + d0 + c];
    }
    __syncthreads();
#pragma unroll
    for (int i = 0; i < 16; ++i) {
      int idx = threadIdx.x + i * 256;
      int r = idx >> 6, c = idx & 63;
      vt[((size_t)bh * 128 + d0 + r) * 2048 + s0 + c] = t[c][r];
    }
  }
}

// ---------------- balanced 2-way split-K flash attention + fused merge -----
// LDS dbuf K+V via async DMA; defer-max softmax; setprio on MFMA clusters.
// After each pass's partial store, a device-scope atomic on flags[bh*16+qt]
// detects the second-finishing half, which merges both partials -> y.
// Flag result broadcast through dead Ks[0][0] LDS (LDS stays exactly 80KB).
__global__ __launch_bounds__(256) void attn_split(const short* __restrict__ qf,
                                                  const short* __restrict__ kf,
                                                  const short* __restrict__ vt,
                                                  short* __restrict__ part,
                                                  float2* __restrict__ ml,
                                                  short* __restrict__ y,
                                                  int* __restrict__ flags) {
  __shared__ short Ks[2][64 * 128];  // [kpos][d], chunk-swizzled
  __shared__ short Vs[2][128 * 64];  // [d][kpos], chunk-swizzled
  __shared__ short Pw[4][32 * 64];   // per-wave P, stride 64, 3-bit XOR swz
  const int lid = blockIdx.x;
  const int bh = (lid & 7) * 4 + ((lid >> 3) & 3);  // 4 bh per XCD
  const int x = lid >> 5;
  const int tid = threadIdx.x;
  const int wave = tid >> 6, lane = tid & 63;
  const int quad = lane >> 4, l15 = lane & 15;
  const int krow_l = tid >> 4;
  const int kcol_sw = ((tid & 15) ^ krow_l) * 8;
  const int vrow_l = tid >> 3;
  const int vcol_sw = ((tid & 7) ^ (vrow_l & 7)) * 8;
  const short* kgB = kf + (((size_t)bh * 2048) + krow_l) * 128 + kcol_sw;
  const short* vgB = vt + ((size_t)bh * 128 + vrow_l) * 2048 + vcol_sw;
  const int pswz = l15 & 14;  // XOR on 8B-chunk index bits 1..3

  for (int pass = 0; pass < 2; ++pass) {
    const int qt = pass == 0 ? x : 15 - x;
    const int ks = pass == 0 ? 0 : qt + 1;
    const int ke = (qt + 1) << pass;
    const int q0w = qt * 128 + wave * 32;

    bf16x8 qfr[2][4];
#pragma unroll
    for (int mi = 0; mi < 2; ++mi) {
      const short* qp = qf + (((size_t)bh * 2048) + q0w + mi * 16 + l15) * 128;
#pragma unroll
      for (int kc = 0; kc < 4; ++kc)
        qfr[mi][kc] = *(const bf16x8*)(qp + kc * 32 + quad * 8);
    }
    float m_i[2] = {-INFINITY, -INFINITY};
    float l_i[2] = {0.f, 0.f};  // per-lane partial sums (reduced at pass end)
    f32x4 O[2][8];
#pragma unroll
    for (int mi = 0; mi < 2; ++mi)
#pragma unroll
      for (int dt = 0; dt < 8; ++dt) O[mi][dt] = {0.f, 0.f, 0.f, 0.f};

    // prologue: stage first tile into buf 0
    {
      const short* kg = kgB + (size_t)ks * 64 * 128;
      const short* vg = vgB + ks * 64;
#pragma unroll
      for (int i = 0; i < 4; ++i) {
        async16(kg + (size_t)i * 16 * 128, &Ks[0][i * 2048 + tid * 8]);
        async16(vg + (size_t)i * 32 * 2048, &Vs[0][i * 2048 + tid * 8]);
      }
    }
    wait_vm0();
    __syncthreads();

    int cur = 0;
    for (int kt = ks; kt < ke; ++kt) {
      const int k0 = kt * 64;
      if (kt + 1 < ke) {  // DMA next tile into the other buffer (no barrier)
        const short* kg = kgB + (size_t)(k0 + 64) * 128;
        const short* vg = vgB + (k0 + 64);
#pragma unroll
        for (int i = 0; i < 4; ++i) {
          async16(kg + (size_t)i * 16 * 128, &Ks[cur ^ 1][i * 2048 + tid * 8]);
          async16(vg + (size_t)i * 32 * 2048, &Vs[cur ^ 1][i * 2048 + tid * 8]);
        }
      }

      // S^T = K @ Q^T  (m=kpos 64, n=qrow 32); lane col l15 = q-row
      f32x4 St[2][4];
#pragma unroll
      for (int mi = 0; mi < 2; ++mi)
#pragma unroll
        for (int j = 0; j < 4; ++j) St[mi][j] = {0.f, 0.f, 0.f, 0.f};
      __builtin_amdgcn_s_setprio(1);
#pragma unroll
      for (int kc = 0; kc < 4; ++kc) {
        bf16x8 kb[4];
#pragma unroll
        for (int j = 0; j < 4; ++j)
          kb[j] = *(const bf16x8*)&Ks[cur][(j * 16 + l15) * 128 +
                                          (((kc * 4 + quad) ^ l15) & 15) * 8];
#pragma unroll
        for (int mi = 0; mi < 2; ++mi)
#pragma unroll
          for (int j = 0; j < 4; ++j)
            St[mi][j] = MFMA16(kb[j], qfr[mi][kc], St[mi][j]);
      }
      __builtin_amdgcn_s_setprio(0);

      if (kt >= 2 * qt) {  // diagonal: causal mask
#pragma unroll
        for (int mi = 0; mi < 2; ++mi)
#pragma unroll
          for (int j = 0; j < 4; ++j)
#pragma unroll
            for (int r = 0; r < 4; ++r)
              if (k0 + j * 16 + quad * 4 + r > q0w + mi * 16 + l15)
                St[mi][j][r] = -INFINITY;
      }

      // online softmax: defer-max, per-lane trigger, per-lane partial l
#pragma unroll
      for (int mi = 0; mi < 2; ++mi) {
        float mt = -INFINITY;  // per-lane local max over 16 vals
#pragma unroll
        for (int j = 0; j < 4; ++j)
#pragma unroll
          for (int r = 0; r < 4; ++r) mt = fmaxf(mt, St[mi][j][r]);
        if (!__all(mt <= m_i[mi] + 8.f)) {
          mt = fmaxf(mt, __shfl_xor(mt, 16));
          mt = fmaxf(mt, __shfl_xor(mt, 32));
          float mnew = fmaxf(m_i[mi], mt);  // finite: trigger implies finite mt
          float a = __builtin_amdgcn_exp2f(m_i[mi] - mnew);  // -inf -> 0
          m_i[mi] = mnew;
          l_i[mi] *= a;
#pragma unroll
          for (int dt = 0; dt < 8; ++dt)
#pragma unroll
            for (int r = 0; r < 4; ++r) O[mi][dt][r] *= a;
        }
        float ms = (m_i[mi] == -INFINITY) ? 0.f : m_i[mi];
        float ps = 0.f;
#pragma unroll
        for (int j = 0; j < 4; ++j)
#pragma unroll
          for (int r = 0; r < 4; ++r) {
            float p = __builtin_amdgcn_exp2f(St[mi][j][r] - ms);
            St[mi][j][r] = p;
            ps += p;
          }
        l_i[mi] += ps;  // per-lane partial; cross-quad reduce at pass end
      }

      // P (truncated bf16) -> per-wave LDS, stride 64, chunk-XOR swizzle
#pragma unroll
      for (int mi = 0; mi < 2; ++mi) {
        int pr = mi * 16 + l15;
#pragma unroll
        for (int j = 0; j < 4; ++j) {
          u32 u0 = (fbits(St[mi][j][1]) & 0xffff0000u) | (fbits(St[mi][j][0]) >> 16);
          u32 u1 = (fbits(St[mi][j][3]) & 0xffff0000u) | (fbits(St[mi][j][2]) >> 16);
          uint2 pk; pk.x = u0; pk.y = u1;
          int c8s = (j * 4 + quad) ^ pswz;
          *(uint2*)&Pw[wave][pr * 64 + c8s * 4] = pk;
        }
      }

      // O^T += V^T-frag @ P-frag
      __builtin_amdgcn_s_setprio(1);
#pragma unroll
      for (int kc2 = 0; kc2 < 2; ++kc2) {
        bf16x8 pa[2];
#pragma unroll
        for (int mi = 0; mi < 2; ++mi) {
          int pr = mi * 16 + l15;
          int c8s = (kc2 * 8 + quad * 2) ^ pswz;
          pa[mi] = *(const bf16x8*)&Pw[wave][pr * 64 + c8s * 4];
        }
#pragma unroll
        for (int dt = 0; dt < 8; ++dt) {
          bf16x8 vb = *(const bf16x8*)&Vs[cur][(dt * 16 + l15) * 64 +
                                              (((kc2 * 4 + quad) ^ (l15 & 7)) & 7) * 8];
#pragma unroll
          for (int mi = 0; mi < 2; ++mi)
            O[mi][dt] = MFMA16(vb, pa[mi], O[mi][dt]);
        }
      }
      __builtin_amdgcn_s_setprio(0);

      wait_vm0();       // next tile's DMA done (overlapped by compute above)
      __syncthreads();  // all waves done reading cur + all DMAs drained
      cur ^= 1;
    }

    // store partial O as bf16: [qrow][d]
    const int pidx = (bh * 16 + qt) * 2 + pass;
    short* pb = part + (size_t)pidx * 128 * 128;
#pragma unroll
    for (int mi = 0; mi < 2; ++mi) {
      int qrow = wave * 32 + mi * 16 + l15;
#pragma unroll
      for (int dt = 0; dt < 8; ++dt) {
        short4 o;
        o.x = f2bs(O[mi][dt][0]); o.y = f2bs(O[mi][dt][1]);
        o.z = f2bs(O[mi][dt][2]); o.w = f2bs(O[mi][dt][3]);
        *(short4*)&pb[(size_t)qrow * 128 + dt * 16 + quad * 4] = o;
      }
    }
    // cross-quad reduce of per-lane l partials (all lanes execute shfls)
    float lr[2];
#pragma unroll
    for (int mi = 0; mi < 2; ++mi) {
      float v = l_i[mi];
      v += __shfl_xor(v, 16);
      v += __shfl_xor(v, 32);
      lr[mi] = v;
    }
    if (quad == 0) {
#pragma unroll
      for (int mi = 0; mi < 2; ++mi) {
        float2 v; v.x = m_i[mi]; v.y = lr[mi];
        ml[pidx * 128 + wave * 32 + mi * 16 + l15] = v;
      }
    }

    // ---- fused merge: second block to finish (bh,qt) merges both halves --
    __threadfence();   // release: my partial+ml stores device-visible
    __syncthreads();   // all threads of this block have fenced
    if (tid == 0) *(int*)&Ks[0][0] = atomicAdd(&flags[bh * 16 + qt], 1);
    __syncthreads();
    const int arrival = *(const int*)&Ks[0][0];
    __syncthreads();   // flag consumed by all before Ks[0] reuse / divergence
    if (arrival == 1) {
      __threadfence(); // acquire: partner's stores visible
      const int p1 = (bh * 16 + qt) * 2, p2 = p1 + 1;
      const int row = tid >> 1, d0 = (tid & 1) * 64;
      float2 a = ml[p1 * 128 + row], c = ml[p2 * 128 + row];
      float mm = fmaxf(a.x, c.x);  // a.x (first half) always finite
      float a1 = __builtin_amdgcn_exp2f(a.x - mm);
      float a2 = __builtin_amdgcn_exp2f(c.x - mm);
      float invl = 1.f / (a.y * a1 + c.y * a2);
      a1 *= invl; a2 *= invl;
      const short* s1 = part + ((size_t)p1 * 128 + row) * 128 + d0;
      const short* s2 = part + ((size_t)p2 * 128 + row) * 128 + d0;
      const int bb = bh >> 4, hh = bh & 15;
      short* yp = y + (((size_t)bb * 2048 + qt * 128 + row) * 16 + hh) * 128 + d0;
#pragma unroll
      for (int j = 0; j < 16; ++j) {
        short4 v1 = *(const short4*)(s1 + j * 4);
        short4 v2 = *(const short4*)(s2 + j * 4);
        short4 o;
        o.x = f2bs(bs2f(v1.x) * a1 + bs2f(v2.x) * a2);
        o.y = f2bs(bs2f(v1.y) * a1 + bs2f(v2.y) * a2);
        o.z = f2bs(bs2f(v1.z) * a1 + bs2f(v2.z) * a2);
        o.w = f2bs(bs2f(v1.w) * a1 + bs2f(v2.w) * a2);
        *(short4*)(yp + j * 4) = o;
      }
    }
  }
}

extern "C" void kernel_launch(void* const* d_in, const int* in_sizes, int n_in,
                              void* d_out, int out_size, void* d_ws, size_t ws_size,
                              hipStream_t stream) {
  const float* hs   = (const float*)d_in[0];
  const float* Wkvd = (const float*)d_in[1];
  const float* Wqd  = (const float*)d_in[2];
  const float* Wku  = (const float*)d_in[3];
  const float* Wqu  = (const float*)d_in[4];
  const float* Wvu  = (const float*)d_in[5];
  const float* Wrk  = (const float*)d_in[6];
  const float* Wrq  = (const float*)d_in[7];
  const float* Wo   = (const float*)d_in[8];
  float* out = (float*)d_out;
  char* ws = (char*)d_ws;
  const size_t MB = 1024ull * 1024ull;

  short* hs_b = (short*)(ws + 0 * MB);     // 16 MB
  short* W1t  = (short*)(ws + 16 * MB);    // (1536,2048): kvd|qd|rk ^T
  short* W2t  = (short*)(ws + 22 * MB);    // (3072,256): ku|vu ^T
  short* W3t  = W2t + 3072 * 256;          // (2048,256): qu|rq ^T — CONTIGUOUS
                                           //  after W2t (gemm23 requires it)
  short* C1   = (short*)(ws + 25 * MB);    // (4096,1536): kv_d|q_d|k_r
  short* C2   = (short*)(ws + 37 * MB);    // (4096,3072): k_c|v
  short* C3   = (short*)(ws + 61 * MB);    // (4096,2048): q_c|q_r
  short* Wo_t = (short*)(ws + 77 * MB);    // (2048,2048)
  short* q_f  = (short*)(ws + 85 * MB);    // (32,2048,128)
  short* k_f  = (short*)(ws + 101 * MB);
  short* v_t  = (short*)(ws + 117 * MB);   // (32,128,2048)
  short* y_b  = (short*)(ws + 133 * MB);   // (b,s,h,d)
  short*  partb = (short*)(ws + 0 * MB);   // overlay: 1024x128x128 bf16 (32 MB)
  float2* mlb   = (float2*)(ws + 32 * MB); // 1 MB (inside dead C1 at attn time)
  int*    flagsb = (int*)(ws + 33 * MB);   // 512 ints (inside dead C1)

  dim3 blk(256);
  prep_all<<<dim3(16640), blk, 0, stream>>>(hs, Wkvd, Wqd, Wku, Wqu, Wvu, Wrk,
                                            Wrq, Wo, hs_b, W1t, W2t, W3t, Wo_t);

  gemm_bt<short><<<dim3(12, 32), blk, 0, stream>>>(hs_b, 2048, W1t, 2048, C1, 1536, 2048);
  gemm23<<<dim3(40, 32), blk, 0, stream>>>(C1, W2t, C2, C3);

  rope_vtrans<<<dim3(34816), blk, 0, stream>>>(C3, C2, C1, q_f, k_f, v_t);

  // Zero merge flags HERE — after gemm1/gemm23/rope have finished writing and
  // reading C1 (flags live inside C1's extent). Stream order guarantees the
  // memset lands between C1's last use and attn_split's atomics. (r8 bug:
  // this memset was at the top of the stream and gemm1's C1 writes clobbered
  // the zeroed flags.)
  hipMemsetAsync(flagsb, 0, 512 * sizeof(int), stream);

  attn_split<<<dim3(512), blk, 0, stream>>>(q_f, k_f, v_t, partb, mlb, y_b, flagsb);

  gemm_bt<float><<<dim3(16, 32), blk, 0, stream>>>(y_b, 2048, Wo_t, 2048, out, 2048, 2048);
}

// Round 10
// 351.391 us; speedup vs baseline: 1.5558x; 1.5558x over previous
//
#include <hip/hip_runtime.h>
#include <hip/hip_bf16.h>
#include <math.h>

// ---------------------------------------------------------------------------
// MLA forward, bf16 MFMA.
// r10 = BK=64 GEMMs (r9's, verified; worth ~34us vs BK=32) + r7's attn
// (separate attn_merge kernel, XCD-matched grids, NO device fences).
// ROUND-9 LESSON: __threadfence on gfx950 invalidates the per-XCD L2 —
// in-kernel cross-block merge destroyed K/V L2 locality (attn 84 -> 313us).
// Separate-kernel merge is far cheaper than fence-based in-kernel handoff.
// ROUND-4 LESSON: never force min-waves launch_bounds (VGPR cap -> spill).
// ROUND-5 LESSON: extra split-K ways cost ~16MB partial traffic per way.
// ROUND-6/8 LESSON: audit overlay LIFETIMES against the full stream schedule.
// B=2 S=2048 H=2048 nh=16 hd=128 rd=64 L=256
// ---------------------------------------------------------------------------

typedef __attribute__((ext_vector_type(8))) short bf16x8;
typedef __attribute__((ext_vector_type(4))) float f32x4;
typedef unsigned int u32;

#define MFMA16(a, b, c) __builtin_amdgcn_mfma_f32_16x16x32_bf16(a, b, c, 0, 0, 0)

__device__ __forceinline__ short f2bs(float f) {
  __hip_bfloat16 h = __float2bfloat16(f);
  return *reinterpret_cast<short*>(&h);
}
__device__ __forceinline__ float bs2f(short s) {
  union { unsigned int u; float f; } v;
  v.u = ((unsigned int)(unsigned short)s) << 16;
  return v.f;
}
__device__ __forceinline__ u32 fbits(float f) {
  union { float f; u32 u; } v; v.f = f; return v.u;
}

__device__ __forceinline__ void async16(const void* g, void* l) {
  __builtin_amdgcn_global_load_lds(
      (const __attribute__((address_space(1))) u32*)(unsigned long long)g,
      (__attribute__((address_space(3))) u32*)(unsigned int)(unsigned long long)l,
      16, 0, 0);
}
__device__ __forceinline__ void wait_vm0() {
  __builtin_amdgcn_s_waitcnt(0x0f70);  // vmcnt(0) only
}

// ---------------- fused prep: cast hs + all weight transposes --------------
__device__ __forceinline__ void wtrans_tile(const float* __restrict__ W,
                                            short* __restrict__ Wt, int K, int N,
                                            int bx, int by, int tid) {
  __shared__ float t[32][33];
  int k0 = by * 32, n0 = bx * 32;
#pragma unroll
  for (int i = 0; i < 4; ++i) {
    int idx = tid + i * 256;
    int r = idx >> 5, c = idx & 31;
    t[r][c] = W[(size_t)(k0 + r) * N + n0 + c];
  }
  __syncthreads();
#pragma unroll
  for (int i = 0; i < 4; ++i) {
    int idx = tid + i * 256;
    int r = idx >> 5, c = idx & 31;
    Wt[(size_t)(n0 + r) * K + k0 + c] = f2bs(t[c][r]);
  }
}

__global__ __launch_bounds__(256) void prep_all(
    const float* __restrict__ hs, const float* __restrict__ Wkvd,
    const float* __restrict__ Wqd, const float* __restrict__ Wku,
    const float* __restrict__ Wqu, const float* __restrict__ Wvu,
    const float* __restrict__ Wrk, const float* __restrict__ Wrq,
    const float* __restrict__ Wo, short* __restrict__ hs_b,
    short* __restrict__ W1t, short* __restrict__ W2t,
    short* __restrict__ W3t, short* __restrict__ Wo_t) {
  const int b = blockIdx.x, tid = threadIdx.x;
  if (b < 8192) {
    int i = (b * 256 + tid) * 4;
    float4 v = *(const float4*)(hs + i);
    short4 o;
    o.x = f2bs(v.x); o.y = f2bs(v.y); o.z = f2bs(v.z); o.w = f2bs(v.w);
    *(short4*)(hs_b + i) = o;
  } else if (b < 8704) {
    int l = b - 8192; wtrans_tile(Wkvd, W1t, 2048, 256, l & 7, l >> 3, tid);
  } else if (b < 9216) {
    int l = b - 8704; wtrans_tile(Wqd, W1t + 256 * 2048, 2048, 256, l & 7, l >> 3, tid);
  } else if (b < 11264) {
    int l = b - 9216; wtrans_tile(Wrk, W1t + 512 * 2048, 2048, 1024, l & 31, l >> 5, tid);
  } else if (b < 11520) {
    int l = b - 11264; wtrans_tile(Wku, W2t, 256, 1024, l & 31, l >> 5, tid);
  } else if (b < 12032) {
    int l = b - 11520; wtrans_tile(Wvu, W2t + 1024 * 256, 256, 2048, l & 63, l >> 6, tid);
  } else if (b < 12288) {
    int l = b - 12032; wtrans_tile(Wqu, W3t, 256, 1024, l & 31, l >> 5, tid);
  } else if (b < 12544) {
    int l = b - 12288; wtrans_tile(Wrq, W3t + 1024 * 256, 256, 1024, l & 31, l >> 5, tid);
  } else {
    int l = b - 12544; wtrans_tile(Wo, Wo_t, 2048, 2048, l & 63, l >> 6, tid);
  }
}

// ---------------- bf16 MFMA GEMM, BK=64, swizzled staging: C = A @ Bt^T ----
// Staging: LDS[r][c] = global[r][c ^ (r&7)] (chunk=8 shorts); read slot
// (s*4+quad) ^ (l15&7) recovers global chunk s*4+quad (row&7 == l15&7).
__device__ __forceinline__ void cstore(float v, float* p) { *p = v; }
__device__ __forceinline__ void cstore(float v, short* p) { *p = f2bs(v); }

template <typename CT>
__global__ __launch_bounds__(256) void gemm_bt(const short* __restrict__ A, int lda,
                                               const short* __restrict__ Bt, int ldb,
                                               CT* __restrict__ C, int ldc, int K) {
  __shared__ short As[128 * 64];
  __shared__ short Bs[128 * 64];
  const int tid = threadIdx.x;
  const int wave = tid >> 6, lane = tid & 63;
  const int quad = lane >> 4, l15 = lane & 15;
  const int wm = wave & 1, wn = wave >> 1;
  const int row0 = blockIdx.y * 128, col0 = blockIdx.x * 128;
  const int sr = tid >> 3;                    // staging row 0..31 (+i*32)
  const int sc = ((tid & 7) ^ (sr & 7)) * 8;  // inverse-swizzled global chunk
  const short* Ag = A + (size_t)(row0 + sr) * lda + sc;
  const short* Bg = Bt + (size_t)(col0 + sr) * ldb + sc;
  const int rk = l15 & 7;                     // read-side XOR key (row&7)

  f32x4 acc[4][4];
#pragma unroll
  for (int i = 0; i < 4; ++i)
#pragma unroll
    for (int j = 0; j < 4; ++j) acc[i][j] = {0.f, 0.f, 0.f, 0.f};

  for (int k0 = 0; k0 < K; k0 += 64) {
    __syncthreads();
#pragma unroll
    for (int i = 0; i < 4; ++i) {
      async16(Ag + (size_t)(i * 32) * lda + k0, &As[i * 2048 + tid * 8]);
      async16(Bg + (size_t)(i * 32) * ldb + k0, &Bs[i * 2048 + tid * 8]);
    }
    wait_vm0();
    __syncthreads();
#pragma unroll
    for (int s = 0; s < 2; ++s) {
      bf16x8 af[4], bfr[4];
#pragma unroll
      for (int i = 0; i < 4; ++i) {
        af[i]  = *(const bf16x8*)&As[(wm * 64 + i * 16 + l15) * 64 +
                                     ((s * 4 + quad) ^ rk) * 8];
        bfr[i] = *(const bf16x8*)&Bs[(wn * 64 + i * 16 + l15) * 64 +
                                     ((s * 4 + quad) ^ rk) * 8];
      }
#pragma unroll
      for (int i = 0; i < 4; ++i)
#pragma unroll
        for (int j = 0; j < 4; ++j)
          acc[i][j] = MFMA16(af[i], bfr[j], acc[i][j]);
    }
  }
#pragma unroll
  for (int i = 0; i < 4; ++i)
#pragma unroll
    for (int j = 0; j < 4; ++j)
#pragma unroll
      for (int r = 0; r < 4; ++r) {
        int row = row0 + wm * 64 + i * 16 + quad * 4 + r;
        int col = col0 + wn * 64 + j * 16 + l15;
        cstore(acc[i][j][r], &C[(size_t)row * ldc + col]);
      }
}

// ---- fused gemm2+gemm3, BK=64: A=C1(/+256), B rows contiguous W2t|W3t -----
// REQUIRES: W3t == W2t + 3072*256 (enforced in kernel_launch layout).
__global__ __launch_bounds__(256) void gemm23(const short* __restrict__ C1,
                                              const short* __restrict__ W2t,
                                              short* __restrict__ C2,
                                              short* __restrict__ C3) {
  __shared__ short As[128 * 64];
  __shared__ short Bs[128 * 64];
  const int tid = threadIdx.x;
  const int wave = tid >> 6, lane = tid & 63;
  const int quad = lane >> 4, l15 = lane & 15;
  const int wm = wave & 1, wn = wave >> 1;
  const int bx = blockIdx.x;
  const bool isC2 = bx < 24;
  short* C = isC2 ? C2 : C3;
  const int ldc = isC2 ? 3072 : 2048;
  const int colbase = isC2 ? bx * 128 : (bx - 24) * 128;
  const short* A = isC2 ? C1 : C1 + 256;  // kv_d vs q_d columns of C1
  const int row0 = blockIdx.y * 128;
  const int sr = tid >> 3;
  const int sc = ((tid & 7) ^ (sr & 7)) * 8;
  const short* Ag = A + (size_t)(row0 + sr) * 1536 + sc;
  const short* Bg = W2t + (size_t)(bx * 128 + sr) * 256 + sc;  // W3t contiguous
  const int rk = l15 & 7;

  f32x4 acc[4][4];
#pragma unroll
  for (int i = 0; i < 4; ++i)
#pragma unroll
    for (int j = 0; j < 4; ++j) acc[i][j] = {0.f, 0.f, 0.f, 0.f};

  for (int k0 = 0; k0 < 256; k0 += 64) {
    __syncthreads();
#pragma unroll
    for (int i = 0; i < 4; ++i) {
      async16(Ag + (size_t)(i * 32) * 1536 + k0, &As[i * 2048 + tid * 8]);
      async16(Bg + (size_t)(i * 32) * 256 + k0, &Bs[i * 2048 + tid * 8]);
    }
    wait_vm0();
    __syncthreads();
#pragma unroll
    for (int s = 0; s < 2; ++s) {
      bf16x8 af[4], bfr[4];
#pragma unroll
      for (int i = 0; i < 4; ++i) {
        af[i]  = *(const bf16x8*)&As[(wm * 64 + i * 16 + l15) * 64 +
                                     ((s * 4 + quad) ^ rk) * 8];
        bfr[i] = *(const bf16x8*)&Bs[(wn * 64 + i * 16 + l15) * 64 +
                                     ((s * 4 + quad) ^ rk) * 8];
      }
#pragma unroll
      for (int i = 0; i < 4; ++i)
#pragma unroll
        for (int j = 0; j < 4; ++j)
          acc[i][j] = MFMA16(af[i], bfr[j], acc[i][j]);
    }
  }
#pragma unroll
  for (int i = 0; i < 4; ++i)
#pragma unroll
    for (int j = 0; j < 4; ++j)
#pragma unroll
      for (int r = 0; r < 4; ++r) {
        int row = row0 + wm * 64 + i * 16 + quad * 4 + r;
        int col = colbase + wn * 64 + j * 16 + l15;
        cstore(acc[i][j][r], &C[(size_t)row * ldc + col]);
      }
}

// ---------------- fused RoPE-pack + V-transpose ----------------------------
__global__ __launch_bounds__(256) void rope_vtrans(
    const short* __restrict__ c3, const short* __restrict__ c2,
    const short* __restrict__ c1, short* __restrict__ qf,
    short* __restrict__ kf, short* __restrict__ vt) {
  if (blockIdx.x < 32768) {
    const float QSCALE = 0.08838834764831845f * 1.4426950408889634f;
    int idx = blockIdx.x * 256 + threadIdx.x;
    int m = idx >> 11;
    int col = idx & 2047;
    int h = col >> 7;
    int j = col & 127;
    int b = m >> 11, s = m & 2047;
    float oq, ok;
    if (j < 64) {
      oq = bs2f(c3[(size_t)m * 2048 + h * 64 + j]);
      ok = bs2f(c2[(size_t)m * 3072 + h * 64 + j]);
    } else {
      int jr = j - 64;
      int f = jr & 31;
      float ang = (float)s * __expf(-0.2878231366242557f * (float)f);
      float c = __cosf(ang), sn = __sinf(ang);
      size_t qb = (size_t)m * 2048 + 1024 + h * 64;
      size_t kb = (size_t)m * 1536 + 512 + h * 64;
      float xq = bs2f(c3[qb + jr]), xk = bs2f(c1[kb + jr]);
      float rq, rk;
      if (jr < 32) { rq = -bs2f(c3[qb + jr + 32]); rk = -bs2f(c1[kb + jr + 32]); }
      else         { rq =  bs2f(c3[qb + jr - 32]); rk =  bs2f(c1[kb + jr - 32]); }
      oq = fmaf(xq, c, rq * sn);
      ok = fmaf(xk, c, rk * sn);
    }
    size_t dst = (((size_t)b * 16 + h) * 2048 + s) * 128 + j;
    qf[dst] = f2bs(oq * QSCALE);
    kf[dst] = f2bs(ok);
  } else {
    __shared__ short t[64][72];
    const int l = blockIdx.x - 32768;  // 0..2047
    const int bh = ((l & 7) << 2) | ((l >> 3) & 3);  // lid%8 == bh>>2 (XCD)
    const int s0 = ((l >> 5) & 31) * 64;
    const int d0 = ((l >> 10) & 1) * 64;
    const int b = bh >> 4, h = bh & 15;
#pragma unroll
    for (int i = 0; i < 16; ++i) {
      int idx = threadIdx.x + i * 256;
      int r = idx >> 6, c = idx & 63;
      t[r][c] = c2[(size_t)(b * 2048 + s0 + r) * 3072 + 1024 + h * 128 + d0 + c];
    }
    __syncthreads();
#pragma unroll
    for (int i = 0; i < 16; ++i) {
      int idx = threadIdx.x + i * 256;
      int r = idx >> 6, c = idx & 63;
      vt[((size_t)bh * 128 + d0 + r) * 2048 + s0 + c] = t[c][r];
    }
  }
}

// ---------------- balanced 2-way split-K flash attention (v3/r7) -----------
// LDS dbuf K+V via async DMA; one vmcnt(0)+barrier per iter. Defer-max
// softmax: per-lane trigger, per-lane partial l reduced once per pass.
// setprio(1) around MFMA clusters. XCD-local bh. NO device fences (r9).
__global__ __launch_bounds__(256) void attn_split(const short* __restrict__ qf,
                                                  const short* __restrict__ kf,
                                                  const short* __restrict__ vt,
                                                  short* __restrict__ part,
                                                  float2* __restrict__ ml) {
  __shared__ short Ks[2][64 * 128];  // [kpos][d], chunk-swizzled
  __shared__ short Vs[2][128 * 64];  // [d][kpos], chunk-swizzled
  __shared__ short Pw[4][32 * 64];   // per-wave P, stride 64, 3-bit XOR swz
  const int lid = blockIdx.x;
  const int bh = (lid & 7) * 4 + ((lid >> 3) & 3);  // 4 bh per XCD
  const int x = lid >> 5;
  const int tid = threadIdx.x;
  const int wave = tid >> 6, lane = tid & 63;
  const int quad = lane >> 4, l15 = lane & 15;
  const int krow_l = tid >> 4;
  const int kcol_sw = ((tid & 15) ^ krow_l) * 8;
  const int vrow_l = tid >> 3;
  const int vcol_sw = ((tid & 7) ^ (vrow_l & 7)) * 8;
  const short* kgB = kf + (((size_t)bh * 2048) + krow_l) * 128 + kcol_sw;
  const short* vgB = vt + ((size_t)bh * 128 + vrow_l) * 2048 + vcol_sw;
  const int pswz = l15 & 14;  // XOR on 8B-chunk index bits 1..3

  for (int pass = 0; pass < 2; ++pass) {
    const int qt = pass == 0 ? x : 15 - x;
    const int ks = pass == 0 ? 0 : qt + 1;
    const int ke = (qt + 1) << pass;
    const int q0w = qt * 128 + wave * 32;

    bf16x8 qfr[2][4];
#pragma unroll
    for (int mi = 0; mi < 2; ++mi) {
      const short* qp = qf + (((size_t)bh * 2048) + q0w + mi * 16 + l15) * 128;
#pragma unroll
      for (int kc = 0; kc < 4; ++kc)
        qfr[mi][kc] = *(const bf16x8*)(qp + kc * 32 + quad * 8);
    }
    float m_i[2] = {-INFINITY, -INFINITY};
    float l_i[2] = {0.f, 0.f};  // per-lane partial sums (reduced at pass end)
    f32x4 O[2][8];
#pragma unroll
    for (int mi = 0; mi < 2; ++mi)
#pragma unroll
      for (int dt = 0; dt < 8; ++dt) O[mi][dt] = {0.f, 0.f, 0.f, 0.f};

    // prologue: stage first tile into buf 0
    {
      const short* kg = kgB + (size_t)ks * 64 * 128;
      const short* vg = vgB + ks * 64;
#pragma unroll
      for (int i = 0; i < 4; ++i) {
        async16(kg + (size_t)i * 16 * 128, &Ks[0][i * 2048 + tid * 8]);
        async16(vg + (size_t)i * 32 * 2048, &Vs[0][i * 2048 + tid * 8]);
      }
    }
    wait_vm0();
    __syncthreads();

    int cur = 0;
    for (int kt = ks; kt < ke; ++kt) {
      const int k0 = kt * 64;
      if (kt + 1 < ke) {  // DMA next tile into the other buffer (no barrier)
        const short* kg = kgB + (size_t)(k0 + 64) * 128;
        const short* vg = vgB + (k0 + 64);
#pragma unroll
        for (int i = 0; i < 4; ++i) {
          async16(kg + (size_t)i * 16 * 128, &Ks[cur ^ 1][i * 2048 + tid * 8]);
          async16(vg + (size_t)i * 32 * 2048, &Vs[cur ^ 1][i * 2048 + tid * 8]);
        }
      }

      // S^T = K @ Q^T  (m=kpos 64, n=qrow 32); lane col l15 = q-row
      f32x4 St[2][4];
#pragma unroll
      for (int mi = 0; mi < 2; ++mi)
#pragma unroll
        for (int j = 0; j < 4; ++j) St[mi][j] = {0.f, 0.f, 0.f, 0.f};
      __builtin_amdgcn_s_setprio(1);
#pragma unroll
      for (int kc = 0; kc < 4; ++kc) {
        bf16x8 kb[4];
#pragma unroll
        for (int j = 0; j < 4; ++j)
          kb[j] = *(const bf16x8*)&Ks[cur][(j * 16 + l15) * 128 +
                                          (((kc * 4 + quad) ^ l15) & 15) * 8];
#pragma unroll
        for (int mi = 0; mi < 2; ++mi)
#pragma unroll
          for (int j = 0; j < 4; ++j)
            St[mi][j] = MFMA16(kb[j], qfr[mi][kc], St[mi][j]);
      }
      __builtin_amdgcn_s_setprio(0);

      if (kt >= 2 * qt) {  // diagonal: causal mask
#pragma unroll
        for (int mi = 0; mi < 2; ++mi)
#pragma unroll
          for (int j = 0; j < 4; ++j)
#pragma unroll
            for (int r = 0; r < 4; ++r)
              if (k0 + j * 16 + quad * 4 + r > q0w + mi * 16 + l15)
                St[mi][j][r] = -INFINITY;
      }

      // online softmax: defer-max, per-lane trigger, per-lane partial l
#pragma unroll
      for (int mi = 0; mi < 2; ++mi) {
        float mt = -INFINITY;  // per-lane local max over 16 vals
#pragma unroll
        for (int j = 0; j < 4; ++j)
#pragma unroll
          for (int r = 0; r < 4; ++r) mt = fmaxf(mt, St[mi][j][r]);
        if (!__all(mt <= m_i[mi] + 8.f)) {
          mt = fmaxf(mt, __shfl_xor(mt, 16));
          mt = fmaxf(mt, __shfl_xor(mt, 32));
          float mnew = fmaxf(m_i[mi], mt);  // finite: trigger implies finite mt
          float a = __builtin_amdgcn_exp2f(m_i[mi] - mnew);  // -inf -> 0
          m_i[mi] = mnew;
          l_i[mi] *= a;
#pragma unroll
          for (int dt = 0; dt < 8; ++dt)
#pragma unroll
            for (int r = 0; r < 4; ++r) O[mi][dt][r] *= a;
        }
        float ms = (m_i[mi] == -INFINITY) ? 0.f : m_i[mi];
        float ps = 0.f;
#pragma unroll
        for (int j = 0; j < 4; ++j)
#pragma unroll
          for (int r = 0; r < 4; ++r) {
            float p = __builtin_amdgcn_exp2f(St[mi][j][r] - ms);
            St[mi][j][r] = p;
            ps += p;
          }
        l_i[mi] += ps;  // per-lane partial; cross-quad reduce at pass end
      }

      // P (truncated bf16) -> per-wave LDS, stride 64, chunk-XOR swizzle
#pragma unroll
      for (int mi = 0; mi < 2; ++mi) {
        int pr = mi * 16 + l15;
#pragma unroll
        for (int j = 0; j < 4; ++j) {
          u32 u0 = (fbits(St[mi][j][1]) & 0xffff0000u) | (fbits(St[mi][j][0]) >> 16);
          u32 u1 = (fbits(St[mi][j][3]) & 0xffff0000u) | (fbits(St[mi][j][2]) >> 16);
          uint2 pk; pk.x = u0; pk.y = u1;
          int c8s = (j * 4 + quad) ^ pswz;
          *(uint2*)&Pw[wave][pr * 64 + c8s * 4] = pk;
        }
      }

      // O^T += V^T-frag @ P-frag
      __builtin_amdgcn_s_setprio(1);
#pragma unroll
      for (int kc2 = 0; kc2 < 2; ++kc2) {
        bf16x8 pa[2];
#pragma unroll
        for (int mi = 0; mi < 2; ++mi) {
          int pr = mi * 16 + l15;
          int c8s = (kc2 * 8 + quad * 2) ^ pswz;
          pa[mi] = *(const bf16x8*)&Pw[wave][pr * 64 + c8s * 4];
        }
#pragma unroll
        for (int dt = 0; dt < 8; ++dt) {
          bf16x8 vb = *(const bf16x8*)&Vs[cur][(dt * 16 + l15) * 64 +
                                              (((kc2 * 4 + quad) ^ (l15 & 7)) & 7) * 8];
#pragma unroll
          for (int mi = 0; mi < 2; ++mi)
            O[mi][dt] = MFMA16(vb, pa[mi], O[mi][dt]);
        }
      }
      __builtin_amdgcn_s_setprio(0);

      wait_vm0();       // next tile's DMA done (overlapped by compute above)
      __syncthreads();  // all waves done reading cur + all DMAs drained
      cur ^= 1;
    }

    // store partial O as bf16: [qrow][d]
    const int pidx = (bh * 16 + qt) * 2 + pass;
    short* pb = part + (size_t)pidx * 128 * 128;
#pragma unroll
    for (int mi = 0; mi < 2; ++mi) {
      int qrow = wave * 32 + mi * 16 + l15;
#pragma unroll
      for (int dt = 0; dt < 8; ++dt) {
        short4 o;
        o.x = f2bs(O[mi][dt][0]); o.y = f2bs(O[mi][dt][1]);
        o.z = f2bs(O[mi][dt][2]); o.w = f2bs(O[mi][dt][3]);
        *(short4*)&pb[(size_t)qrow * 128 + dt * 16 + quad * 4] = o;
      }
    }
    // cross-quad reduce of per-lane l partials (all lanes execute shfls)
    float lr[2];
#pragma unroll
    for (int mi = 0; mi < 2; ++mi) {
      float v = l_i[mi];
      v += __shfl_xor(v, 16);
      v += __shfl_xor(v, 32);
      lr[mi] = v;
    }
    if (quad == 0) {
#pragma unroll
      for (int mi = 0; mi < 2; ++mi) {
        float2 v; v.x = m_i[mi]; v.y = lr[mi];
        ml[pidx * 128 + wave * 32 + mi * 16 + l15] = v;
      }
    }
  }
}

// ---------------- merge two partials per q-tile ----------------------------
// 1-D grid 512 with XCD-matched decode: lid%8 == bh>>2, so each merge block
// reads the partials its own XCD's L2 just absorbed from attn_split.
__global__ __launch_bounds__(256) void attn_merge(const short* __restrict__ part,
                                                  const float2* __restrict__ ml,
                                                  short* __restrict__ y) {
  const int l = blockIdx.x;
  const int bh = ((l & 7) << 2) | ((l >> 3) & 3);
  const int qt = (l >> 5) & 15;
  const int b = bh >> 4, h = bh & 15;
  const int row = threadIdx.x >> 1, d0 = (threadIdx.x & 1) * 64;
  const int p1 = (bh * 16 + qt) * 2, p2 = p1 + 1;
  float2 a = ml[p1 * 128 + row], c = ml[p2 * 128 + row];
  float m = fmaxf(a.x, c.x);
  float a1 = __builtin_amdgcn_exp2f(a.x - m);
  float a2 = __builtin_amdgcn_exp2f(c.x - m);
  float invl = 1.f / (a.y * a1 + c.y * a2);
  a1 *= invl; a2 *= invl;
  const short* s1 = part + ((size_t)p1 * 128 + row) * 128 + d0;
  const short* s2 = part + ((size_t)p2 * 128 + row) * 128 + d0;
  short* yp = y + (((size_t)b * 2048 + qt * 128 + row) * 16 + h) * 128 + d0;
#pragma unroll
  for (int j = 0; j < 16; ++j) {
    short4 v1 = *(const short4*)(s1 + j * 4);
    short4 v2 = *(const short4*)(s2 + j * 4);
    short4 o;
    o.x = f2bs(bs2f(v1.x) * a1 + bs2f(v2.x) * a2);
    o.y = f2bs(bs2f(v1.y) * a1 + bs2f(v2.y) * a2);
    o.z = f2bs(bs2f(v1.z) * a1 + bs2f(v2.z) * a2);
    o.w = f2bs(bs2f(v1.w) * a1 + bs2f(v2.w) * a2);
    *(short4*)(yp + j * 4) = o;
  }
}

extern "C" void kernel_launch(void* const* d_in, const int* in_sizes, int n_in,
                              void* d_out, int out_size, void* d_ws, size_t ws_size,
                              hipStream_t stream) {
  const float* hs   = (const float*)d_in[0];
  const float* Wkvd = (const float*)d_in[1];
  const float* Wqd  = (const float*)d_in[2];
  const float* Wku  = (const float*)d_in[3];
  const float* Wqu  = (const float*)d_in[4];
  const float* Wvu  = (const float*)d_in[5];
  const float* Wrk  = (const float*)d_in[6];
  const float* Wrq  = (const float*)d_in[7];
  const float* Wo   = (const float*)d_in[8];
  float* out = (float*)d_out;
  char* ws = (char*)d_ws;
  const size_t MB = 1024ull * 1024ull;

  short* hs_b = (short*)(ws + 0 * MB);     // 16 MB
  short* W1t  = (short*)(ws + 16 * MB);    // (1536,2048): kvd|qd|rk ^T
  short* W2t  = (short*)(ws + 22 * MB);    // (3072,256): ku|vu ^T
  short* W3t  = W2t + 3072 * 256;          // (2048,256): qu|rq ^T — CONTIGUOUS
                                           //  after W2t (gemm23 requires it)
  short* C1   = (short*)(ws + 25 * MB);    // (4096,1536): kv_d|q_d|k_r
  short* C2   = (short*)(ws + 37 * MB);    // (4096,3072): k_c|v
  short* C3   = (short*)(ws + 61 * MB);    // (4096,2048): q_c|q_r
  short* Wo_t = (short*)(ws + 77 * MB);    // (2048,2048)
  short* q_f  = (short*)(ws + 85 * MB);    // (32,2048,128)
  short* k_f  = (short*)(ws + 101 * MB);
  short* v_t  = (short*)(ws + 117 * MB);   // (32,128,2048)
  short* y_b  = (short*)(ws + 133 * MB);   // (b,s,h,d)
  short*  partb = (short*)(ws + 0 * MB);   // overlay: 1024x128x128 bf16 (32 MB)
  float2* mlb   = (float2*)(ws + 32 * MB); // 1 MB

  dim3 blk(256);
  prep_all<<<dim3(16640), blk, 0, stream>>>(hs, Wkvd, Wqd, Wku, Wqu, Wvu, Wrk,
                                            Wrq, Wo, hs_b, W1t, W2t, W3t, Wo_t);

  gemm_bt<short><<<dim3(12, 32), blk, 0, stream>>>(hs_b, 2048, W1t, 2048, C1, 1536, 2048);
  gemm23<<<dim3(40, 32), blk, 0, stream>>>(C1, W2t, C2, C3);

  rope_vtrans<<<dim3(34816), blk, 0, stream>>>(C3, C2, C1, q_f, k_f, v_t);

  attn_split<<<dim3(512), blk, 0, stream>>>(q_f, k_f, v_t, partb, mlb);
  attn_merge<<<dim3(512), blk, 0, stream>>>(partb, mlb, y_b);

  gemm_bt<float><<<dim3(16, 32), blk, 0, stream>>>(y_b, 2048, Wo_t, 2048, out, 2048, 2048);
}

// Round 11
// 331.040 us; speedup vs baseline: 1.6515x; 1.0615x over previous
//
#include <hip/hip_runtime.h>
#include <hip/hip_bf16.h>
#include <math.h>

// ---------------------------------------------------------------------------
// MLA forward, bf16 MFMA.
// r11 = r10 GEMM stack (BK=64, verified) + attn v8: QBLK=64, KVBLK=32,
// 2-way split, grid 1024. LDS 36KB -> 4 blocks/CU = 4 waves/SIMD (2x r10)
// with partial traffic UNCHANGED (32MB — the r5 4-way mistake avoided).
// Inner loop = r5's verified KVBLK=32 body with the mi dimension removed
// (wave owns 16 q-rows). Pairing: block x does (qt=x, half0) then
// (qt=31-x, half1) -> 33 k-tiles for every block.
// ROUND-9 LESSON: __threadfence on gfx950 invalidates per-XCD L2 — never
// fence inside an L2-locality-dependent kernel; separate merge kernel.
// ROUND-4 LESSON: never force min-waves launch_bounds (VGPR cap -> spill).
// ROUND-5 LESSON: extra split-K ways cost ~16MB partial traffic per way.
// ROUND-6/8 LESSON: audit overlay LIFETIMES against the full stream schedule.
// B=2 S=2048 H=2048 nh=16 hd=128 rd=64 L=256
// ---------------------------------------------------------------------------

typedef __attribute__((ext_vector_type(8))) short bf16x8;
typedef __attribute__((ext_vector_type(4))) float f32x4;
typedef unsigned int u32;

#define MFMA16(a, b, c) __builtin_amdgcn_mfma_f32_16x16x32_bf16(a, b, c, 0, 0, 0)

__device__ __forceinline__ short f2bs(float f) {
  __hip_bfloat16 h = __float2bfloat16(f);
  return *reinterpret_cast<short*>(&h);
}
__device__ __forceinline__ float bs2f(short s) {
  union { unsigned int u; float f; } v;
  v.u = ((unsigned int)(unsigned short)s) << 16;
  return v.f;
}
__device__ __forceinline__ u32 fbits(float f) {
  union { float f; u32 u; } v; v.f = f; return v.u;
}

__device__ __forceinline__ void async16(const void* g, void* l) {
  __builtin_amdgcn_global_load_lds(
      (const __attribute__((address_space(1))) u32*)(unsigned long long)g,
      (__attribute__((address_space(3))) u32*)(unsigned int)(unsigned long long)l,
      16, 0, 0);
}
__device__ __forceinline__ void wait_vm0() {
  __builtin_amdgcn_s_waitcnt(0x0f70);  // vmcnt(0) only
}

// ---------------- fused prep: cast hs + all weight transposes --------------
__device__ __forceinline__ void wtrans_tile(const float* __restrict__ W,
                                            short* __restrict__ Wt, int K, int N,
                                            int bx, int by, int tid) {
  __shared__ float t[32][33];
  int k0 = by * 32, n0 = bx * 32;
#pragma unroll
  for (int i = 0; i < 4; ++i) {
    int idx = tid + i * 256;
    int r = idx >> 5, c = idx & 31;
    t[r][c] = W[(size_t)(k0 + r) * N + n0 + c];
  }
  __syncthreads();
#pragma unroll
  for (int i = 0; i < 4; ++i) {
    int idx = tid + i * 256;
    int r = idx >> 5, c = idx & 31;
    Wt[(size_t)(n0 + r) * K + k0 + c] = f2bs(t[c][r]);
  }
}

__global__ __launch_bounds__(256) void prep_all(
    const float* __restrict__ hs, const float* __restrict__ Wkvd,
    const float* __restrict__ Wqd, const float* __restrict__ Wku,
    const float* __restrict__ Wqu, const float* __restrict__ Wvu,
    const float* __restrict__ Wrk, const float* __restrict__ Wrq,
    const float* __restrict__ Wo, short* __restrict__ hs_b,
    short* __restrict__ W1t, short* __restrict__ W2t,
    short* __restrict__ W3t, short* __restrict__ Wo_t) {
  const int b = blockIdx.x, tid = threadIdx.x;
  if (b < 8192) {
    int i = (b * 256 + tid) * 4;
    float4 v = *(const float4*)(hs + i);
    short4 o;
    o.x = f2bs(v.x); o.y = f2bs(v.y); o.z = f2bs(v.z); o.w = f2bs(v.w);
    *(short4*)(hs_b + i) = o;
  } else if (b < 8704) {
    int l = b - 8192; wtrans_tile(Wkvd, W1t, 2048, 256, l & 7, l >> 3, tid);
  } else if (b < 9216) {
    int l = b - 8704; wtrans_tile(Wqd, W1t + 256 * 2048, 2048, 256, l & 7, l >> 3, tid);
  } else if (b < 11264) {
    int l = b - 9216; wtrans_tile(Wrk, W1t + 512 * 2048, 2048, 1024, l & 31, l >> 5, tid);
  } else if (b < 11520) {
    int l = b - 11264; wtrans_tile(Wku, W2t, 256, 1024, l & 31, l >> 5, tid);
  } else if (b < 12032) {
    int l = b - 11520; wtrans_tile(Wvu, W2t + 1024 * 256, 256, 2048, l & 63, l >> 6, tid);
  } else if (b < 12288) {
    int l = b - 12032; wtrans_tile(Wqu, W3t, 256, 1024, l & 31, l >> 5, tid);
  } else if (b < 12544) {
    int l = b - 12288; wtrans_tile(Wrq, W3t + 1024 * 256, 256, 1024, l & 31, l >> 5, tid);
  } else {
    int l = b - 12544; wtrans_tile(Wo, Wo_t, 2048, 2048, l & 63, l >> 6, tid);
  }
}

// ---------------- bf16 MFMA GEMM, BK=64, swizzled staging: C = A @ Bt^T ----
__device__ __forceinline__ void cstore(float v, float* p) { *p = v; }
__device__ __forceinline__ void cstore(float v, short* p) { *p = f2bs(v); }

template <typename CT>
__global__ __launch_bounds__(256) void gemm_bt(const short* __restrict__ A, int lda,
                                               const short* __restrict__ Bt, int ldb,
                                               CT* __restrict__ C, int ldc, int K) {
  __shared__ short As[128 * 64];
  __shared__ short Bs[128 * 64];
  const int tid = threadIdx.x;
  const int wave = tid >> 6, lane = tid & 63;
  const int quad = lane >> 4, l15 = lane & 15;
  const int wm = wave & 1, wn = wave >> 1;
  const int row0 = blockIdx.y * 128, col0 = blockIdx.x * 128;
  const int sr = tid >> 3;                    // staging row 0..31 (+i*32)
  const int sc = ((tid & 7) ^ (sr & 7)) * 8;  // inverse-swizzled global chunk
  const short* Ag = A + (size_t)(row0 + sr) * lda + sc;
  const short* Bg = Bt + (size_t)(col0 + sr) * ldb + sc;
  const int rk = l15 & 7;                     // read-side XOR key (row&7)

  f32x4 acc[4][4];
#pragma unroll
  for (int i = 0; i < 4; ++i)
#pragma unroll
    for (int j = 0; j < 4; ++j) acc[i][j] = {0.f, 0.f, 0.f, 0.f};

  for (int k0 = 0; k0 < K; k0 += 64) {
    __syncthreads();
#pragma unroll
    for (int i = 0; i < 4; ++i) {
      async16(Ag + (size_t)(i * 32) * lda + k0, &As[i * 2048 + tid * 8]);
      async16(Bg + (size_t)(i * 32) * ldb + k0, &Bs[i * 2048 + tid * 8]);
    }
    wait_vm0();
    __syncthreads();
#pragma unroll
    for (int s = 0; s < 2; ++s) {
      bf16x8 af[4], bfr[4];
#pragma unroll
      for (int i = 0; i < 4; ++i) {
        af[i]  = *(const bf16x8*)&As[(wm * 64 + i * 16 + l15) * 64 +
                                     ((s * 4 + quad) ^ rk) * 8];
        bfr[i] = *(const bf16x8*)&Bs[(wn * 64 + i * 16 + l15) * 64 +
                                     ((s * 4 + quad) ^ rk) * 8];
      }
#pragma unroll
      for (int i = 0; i < 4; ++i)
#pragma unroll
        for (int j = 0; j < 4; ++j)
          acc[i][j] = MFMA16(af[i], bfr[j], acc[i][j]);
    }
  }
#pragma unroll
  for (int i = 0; i < 4; ++i)
#pragma unroll
    for (int j = 0; j < 4; ++j)
#pragma unroll
      for (int r = 0; r < 4; ++r) {
        int row = row0 + wm * 64 + i * 16 + quad * 4 + r;
        int col = col0 + wn * 64 + j * 16 + l15;
        cstore(acc[i][j][r], &C[(size_t)row * ldc + col]);
      }
}

// ---- fused gemm2+gemm3, BK=64: A=C1(/+256), B rows contiguous W2t|W3t -----
// REQUIRES: W3t == W2t + 3072*256 (enforced in kernel_launch layout).
__global__ __launch_bounds__(256) void gemm23(const short* __restrict__ C1,
                                              const short* __restrict__ W2t,
                                              short* __restrict__ C2,
                                              short* __restrict__ C3) {
  __shared__ short As[128 * 64];
  __shared__ short Bs[128 * 64];
  const int tid = threadIdx.x;
  const int wave = tid >> 6, lane = tid & 63;
  const int quad = lane >> 4, l15 = lane & 15;
  const int wm = wave & 1, wn = wave >> 1;
  const int bx = blockIdx.x;
  const bool isC2 = bx < 24;
  short* C = isC2 ? C2 : C3;
  const int ldc = isC2 ? 3072 : 2048;
  const int colbase = isC2 ? bx * 128 : (bx - 24) * 128;
  const short* A = isC2 ? C1 : C1 + 256;  // kv_d vs q_d columns of C1
  const int row0 = blockIdx.y * 128;
  const int sr = tid >> 3;
  const int sc = ((tid & 7) ^ (sr & 7)) * 8;
  const short* Ag = A + (size_t)(row0 + sr) * 1536 + sc;
  const short* Bg = W2t + (size_t)(bx * 128 + sr) * 256 + sc;  // W3t contiguous
  const int rk = l15 & 7;

  f32x4 acc[4][4];
#pragma unroll
  for (int i = 0; i < 4; ++i)
#pragma unroll
    for (int j = 0; j < 4; ++j) acc[i][j] = {0.f, 0.f, 0.f, 0.f};

  for (int k0 = 0; k0 < 256; k0 += 64) {
    __syncthreads();
#pragma unroll
    for (int i = 0; i < 4; ++i) {
      async16(Ag + (size_t)(i * 32) * 1536 + k0, &As[i * 2048 + tid * 8]);
      async16(Bg + (size_t)(i * 32) * 256 + k0, &Bs[i * 2048 + tid * 8]);
    }
    wait_vm0();
    __syncthreads();
#pragma unroll
    for (int s = 0; s < 2; ++s) {
      bf16x8 af[4], bfr[4];
#pragma unroll
      for (int i = 0; i < 4; ++i) {
        af[i]  = *(const bf16x8*)&As[(wm * 64 + i * 16 + l15) * 64 +
                                     ((s * 4 + quad) ^ rk) * 8];
        bfr[i] = *(const bf16x8*)&Bs[(wn * 64 + i * 16 + l15) * 64 +
                                     ((s * 4 + quad) ^ rk) * 8];
      }
#pragma unroll
      for (int i = 0; i < 4; ++i)
#pragma unroll
        for (int j = 0; j < 4; ++j)
          acc[i][j] = MFMA16(af[i], bfr[j], acc[i][j]);
    }
  }
#pragma unroll
  for (int i = 0; i < 4; ++i)
#pragma unroll
    for (int j = 0; j < 4; ++j)
#pragma unroll
      for (int r = 0; r < 4; ++r) {
        int row = row0 + wm * 64 + i * 16 + quad * 4 + r;
        int col = colbase + wn * 64 + j * 16 + l15;
        cstore(acc[i][j][r], &C[(size_t)row * ldc + col]);
      }
}

// ---------------- fused RoPE-pack + V-transpose ----------------------------
__global__ __launch_bounds__(256) void rope_vtrans(
    const short* __restrict__ c3, const short* __restrict__ c2,
    const short* __restrict__ c1, short* __restrict__ qf,
    short* __restrict__ kf, short* __restrict__ vt) {
  if (blockIdx.x < 32768) {
    const float QSCALE = 0.08838834764831845f * 1.4426950408889634f;
    int idx = blockIdx.x * 256 + threadIdx.x;
    int m = idx >> 11;
    int col = idx & 2047;
    int h = col >> 7;
    int j = col & 127;
    int b = m >> 11, s = m & 2047;
    float oq, ok;
    if (j < 64) {
      oq = bs2f(c3[(size_t)m * 2048 + h * 64 + j]);
      ok = bs2f(c2[(size_t)m * 3072 + h * 64 + j]);
    } else {
      int jr = j - 64;
      int f = jr & 31;
      float ang = (float)s * __expf(-0.2878231366242557f * (float)f);
      float c = __cosf(ang), sn = __sinf(ang);
      size_t qb = (size_t)m * 2048 + 1024 + h * 64;
      size_t kb = (size_t)m * 1536 + 512 + h * 64;
      float xq = bs2f(c3[qb + jr]), xk = bs2f(c1[kb + jr]);
      float rq, rk;
      if (jr < 32) { rq = -bs2f(c3[qb + jr + 32]); rk = -bs2f(c1[kb + jr + 32]); }
      else         { rq =  bs2f(c3[qb + jr - 32]); rk =  bs2f(c1[kb + jr - 32]); }
      oq = fmaf(xq, c, rq * sn);
      ok = fmaf(xk, c, rk * sn);
    }
    size_t dst = (((size_t)b * 16 + h) * 2048 + s) * 128 + j;
    qf[dst] = f2bs(oq * QSCALE);
    kf[dst] = f2bs(ok);
  } else {
    __shared__ short t[64][72];
    const int l = blockIdx.x - 32768;  // 0..2047
    const int bh = ((l & 7) << 2) | ((l >> 3) & 3);  // lid%8 == bh>>2 (XCD)
    const int s0 = ((l >> 5) & 31) * 64;
    const int d0 = ((l >> 10) & 1) * 64;
    const int b = bh >> 4, h = bh & 15;
#pragma unroll
    for (int i = 0; i < 16; ++i) {
      int idx = threadIdx.x + i * 256;
      int r = idx >> 6, c = idx & 63;
      t[r][c] = c2[(size_t)(b * 2048 + s0 + r) * 3072 + 1024 + h * 128 + d0 + c];
    }
    __syncthreads();
#pragma unroll
    for (int i = 0; i < 16; ++i) {
      int idx = threadIdx.x + i * 256;
      int r = idx >> 6, c = idx & 63;
      vt[((size_t)bh * 128 + d0 + r) * 2048 + s0 + c] = t[c][r];
    }
  }
}

// ---------------- 2-way split-K flash attention, QBLK=64 KVBLK=32 ----------
// grid 1024: bh = (lid&7)*4 + ((lid>>3)&3) (XCD-local), x = lid>>5 (0..31).
// pass0: (qt=x, half0 = k-tiles [0, x+1)); pass1: (qt=31-x, half1 =
// [qt+1, 2qt+2)). Every block: 33 k-tiles. LDS 36KB -> 4 blocks/CU.
// Wave owns 16 q-rows (mi dimension removed from the r5-verified body).
__global__ __launch_bounds__(256) void attn_split(const short* __restrict__ qf,
                                                  const short* __restrict__ kf,
                                                  const short* __restrict__ vt,
                                                  short* __restrict__ part,
                                                  float2* __restrict__ ml) {
  __shared__ short Ks[2][32 * 128];  // [kpos][d], granule-swizzled (16KB)
  __shared__ short Vs[2][128 * 32];  // [d][kpos], granule-swizzled (16KB)
  __shared__ short Pw[4][16 * 32];   // per-wave P^T, 2-bit XOR swz (4KB)
  const int lid = blockIdx.x;
  const int bh = (lid & 7) * 4 + ((lid >> 3) & 3);  // 4 bh per XCD
  const int x  = lid >> 5;                          // 0..31
  const int tid = threadIdx.x;
  const int wave = tid >> 6, lane = tid & 63;
  const int quad = lane >> 4, l15 = lane & 15;
  const int krow_l = tid >> 4;                      // 0..15
  const int kcol_sw = ((tid & 15) ^ krow_l) * 8;
  const int vrow_l = tid >> 2;                      // 0..63
  const int vcol_sw = ((tid & 3) ^ (vrow_l & 3) ^ ((vrow_l >> 2) & 3)) * 8;
  const short* kgB = kf + (((size_t)bh * 2048) + krow_l) * 128 + kcol_sw;
  const short* vgB = vt + ((size_t)bh * 128 + vrow_l) * 2048 + vcol_sw;
  const int pswz = l15 & 6;  // XOR on 4-short granule index bits 1..2

  for (int pass = 0; pass < 2; ++pass) {
    const int qt = pass ? 31 - x : x;       // 64-row q-tile index 0..31
    const int ks = pass ? qt + 1 : 0;       // half0 / half1 of causal range
    const int ke = pass ? 2 * (qt + 1) : x + 1;
    const int q0w = qt * 64 + wave * 16;

    bf16x8 qfr[4];
    {
      const short* qp = qf + (((size_t)bh * 2048) + q0w + l15) * 128;
#pragma unroll
      for (int kc = 0; kc < 4; ++kc)
        qfr[kc] = *(const bf16x8*)(qp + kc * 32 + quad * 8);
    }
    float m_i = -INFINITY;
    float l_i = 0.f;  // per-lane partial sum (reduced at pass end)
    f32x4 O[8];
#pragma unroll
    for (int dt = 0; dt < 8; ++dt) O[dt] = {0.f, 0.f, 0.f, 0.f};

    // prologue: stage first tile into buf 0 (2 async16 each per thread)
    {
      const short* kg = kgB + (size_t)ks * 32 * 128;
      const short* vg = vgB + ks * 32;
#pragma unroll
      for (int i = 0; i < 2; ++i) {
        async16(kg + (size_t)i * 16 * 128, &Ks[0][i * 2048 + tid * 8]);
        async16(vg + (size_t)i * 64 * 2048, &Vs[0][i * 2048 + tid * 8]);
      }
    }
    wait_vm0();
    __syncthreads();

    int cur = 0;
    for (int kt = ks; kt < ke; ++kt) {
      const int k0 = kt * 32;
      if (kt + 1 < ke) {  // DMA next tile into the other buffer (no barrier)
        const short* kg = kgB + (size_t)(kt + 1) * 32 * 128;
        const short* vg = vgB + (kt + 1) * 32;
#pragma unroll
        for (int i = 0; i < 2; ++i) {
          async16(kg + (size_t)i * 16 * 128, &Ks[cur ^ 1][i * 2048 + tid * 8]);
          async16(vg + (size_t)i * 64 * 2048, &Vs[cur ^ 1][i * 2048 + tid * 8]);
        }
      }

      // S^T = K @ Q^T  (m=kpos 32, n=qrow 16); lane col l15 = q-row
      f32x4 St[2];
#pragma unroll
      for (int j = 0; j < 2; ++j) St[j] = {0.f, 0.f, 0.f, 0.f};
      __builtin_amdgcn_s_setprio(1);
#pragma unroll
      for (int kc = 0; kc < 4; ++kc) {
        bf16x8 kb[2];
#pragma unroll
        for (int j = 0; j < 2; ++j)
          kb[j] = *(const bf16x8*)&Ks[cur][(j * 16 + l15) * 128 +
                                          (((kc * 4 + quad) ^ l15) & 15) * 8];
#pragma unroll
        for (int j = 0; j < 2; ++j)
          St[j] = MFMA16(kb[j], qfr[kc], St[j]);
      }
      __builtin_amdgcn_s_setprio(0);

      if (kt >= 2 * qt) {  // diagonal: causal mask
#pragma unroll
        for (int j = 0; j < 2; ++j)
#pragma unroll
          for (int r = 0; r < 4; ++r)
            if (k0 + j * 16 + quad * 4 + r > q0w + l15)
              St[j][r] = -INFINITY;
      }

      // online softmax: defer-max, per-lane trigger, per-lane partial l
      {
        float mt = -INFINITY;  // per-lane local max over 8 vals
#pragma unroll
        for (int j = 0; j < 2; ++j)
#pragma unroll
          for (int r = 0; r < 4; ++r) mt = fmaxf(mt, St[j][r]);
        if (!__all(mt <= m_i + 8.f)) {
          mt = fmaxf(mt, __shfl_xor(mt, 16));
          mt = fmaxf(mt, __shfl_xor(mt, 32));
          float mnew = fmaxf(m_i, mt);  // finite: trigger implies finite mt
          float a = __builtin_amdgcn_exp2f(m_i - mnew);  // -inf -> 0
          m_i = mnew;
          l_i *= a;
#pragma unroll
          for (int dt = 0; dt < 8; ++dt)
#pragma unroll
            for (int r = 0; r < 4; ++r) O[dt][r] *= a;
        }
        float ms = (m_i == -INFINITY) ? 0.f : m_i;
        float ps = 0.f;
#pragma unroll
        for (int j = 0; j < 2; ++j)
#pragma unroll
          for (int r = 0; r < 4; ++r) {
            float p = __builtin_amdgcn_exp2f(St[j][r] - ms);
            St[j][r] = p;
            ps += p;
          }
        l_i += ps;
      }

      // P^T (truncated bf16) -> per-wave LDS, 32 shorts/row, granule-XOR swz
      {
        int pr = l15;
#pragma unroll
        for (int j = 0; j < 2; ++j) {
          u32 u0 = (fbits(St[j][1]) & 0xffff0000u) | (fbits(St[j][0]) >> 16);
          u32 u1 = (fbits(St[j][3]) & 0xffff0000u) | (fbits(St[j][2]) >> 16);
          uint2 pk; pk.x = u0; pk.y = u1;
          int g = (j * 4 + quad) ^ pswz;  // logical granule j*4+quad
          *(uint2*)&Pw[wave][pr * 32 + g * 4] = pk;
        }
      }

      // O^T += V^T-frag @ P-frag (K=32: single k-chunk)
      __builtin_amdgcn_s_setprio(1);
      bf16x8 pa;
      {
        int g = (quad * 2) ^ pswz;  // logical granules 2q,2q+1 (pswz even)
        pa = *(const bf16x8*)&Pw[wave][l15 * 32 + g * 4];
      }
#pragma unroll
      for (int dt = 0; dt < 8; ++dt) {
        bf16x8 vb = *(const bf16x8*)&Vs[cur][(dt * 16 + l15) * 32 +
                                            ((quad ^ (l15 & 3) ^ ((l15 >> 2) & 3)) & 3) * 8];
        O[dt] = MFMA16(vb, pa, O[dt]);
      }
      __builtin_amdgcn_s_setprio(0);

      wait_vm0();       // next tile's DMA done (overlapped by compute above)
      __syncthreads();  // all waves done reading cur + all DMAs drained
      cur ^= 1;
    }

    // store partial O as bf16: [qrow 64][d 128]
    const int pidx = (bh * 32 + qt) * 2 + pass;
    short* pb = part + (size_t)pidx * 64 * 128;
    {
      int qrow = wave * 16 + l15;
#pragma unroll
      for (int dt = 0; dt < 8; ++dt) {
        short4 o;
        o.x = f2bs(O[dt][0]); o.y = f2bs(O[dt][1]);
        o.z = f2bs(O[dt][2]); o.w = f2bs(O[dt][3]);
        *(short4*)&pb[(size_t)qrow * 128 + dt * 16 + quad * 4] = o;
      }
    }
    // cross-quad reduce of per-lane l partials (all lanes execute shfls)
    float lr = l_i;
    lr += __shfl_xor(lr, 16);
    lr += __shfl_xor(lr, 32);
    if (quad == 0) {
      float2 v; v.x = m_i; v.y = lr;
      ml[pidx * 64 + wave * 16 + l15] = v;
    }
  }
}

// ---------------- merge two partials per 64-row q-tile ---------------------
// grid 1024, XCD-matched decode (lid%8 == bh>>2): merge reads the partials
// its own XCD's L2 just absorbed from attn_split.
__global__ __launch_bounds__(256) void attn_merge(const short* __restrict__ part,
                                                  const float2* __restrict__ ml,
                                                  short* __restrict__ y) {
  const int l = blockIdx.x;
  const int bh = ((l & 7) << 2) | ((l >> 3) & 3);
  const int qt = (l >> 5) & 31;
  const int b = bh >> 4, h = bh & 15;
  const int row = threadIdx.x >> 2, d0 = (threadIdx.x & 3) * 32;
  const int p1 = (bh * 32 + qt) * 2, p2 = p1 + 1;
  float2 a = ml[p1 * 64 + row], c = ml[p2 * 64 + row];
  float m = fmaxf(a.x, c.x);
  float a1 = __builtin_amdgcn_exp2f(a.x - m);
  float a2 = __builtin_amdgcn_exp2f(c.x - m);
  float invl = 1.f / (a.y * a1 + c.y * a2);
  a1 *= invl; a2 *= invl;
  const short* s1 = part + ((size_t)p1 * 64 + row) * 128 + d0;
  const short* s2 = part + ((size_t)p2 * 64 + row) * 128 + d0;
  short* yp = y + (((size_t)b * 2048 + qt * 64 + row) * 16 + h) * 128 + d0;
#pragma unroll
  for (int j = 0; j < 8; ++j) {
    short4 v1 = *(const short4*)(s1 + j * 4);
    short4 v2 = *(const short4*)(s2 + j * 4);
    short4 o;
    o.x = f2bs(bs2f(v1.x) * a1 + bs2f(v2.x) * a2);
    o.y = f2bs(bs2f(v1.y) * a1 + bs2f(v2.y) * a2);
    o.z = f2bs(bs2f(v1.z) * a1 + bs2f(v2.z) * a2);
    o.w = f2bs(bs2f(v1.w) * a1 + bs2f(v2.w) * a2);
    *(short4*)(yp + j * 4) = o;
  }
}

extern "C" void kernel_launch(void* const* d_in, const int* in_sizes, int n_in,
                              void* d_out, int out_size, void* d_ws, size_t ws_size,
                              hipStream_t stream) {
  const float* hs   = (const float*)d_in[0];
  const float* Wkvd = (const float*)d_in[1];
  const float* Wqd  = (const float*)d_in[2];
  const float* Wku  = (const float*)d_in[3];
  const float* Wqu  = (const float*)d_in[4];
  const float* Wvu  = (const float*)d_in[5];
  const float* Wrk  = (const float*)d_in[6];
  const float* Wrq  = (const float*)d_in[7];
  const float* Wo   = (const float*)d_in[8];
  float* out = (float*)d_out;
  char* ws = (char*)d_ws;
  const size_t MB = 1024ull * 1024ull;

  short* hs_b = (short*)(ws + 0 * MB);     // 16 MB
  short* W1t  = (short*)(ws + 16 * MB);    // (1536,2048): kvd|qd|rk ^T
  short* W2t  = (short*)(ws + 22 * MB);    // (3072,256): ku|vu ^T
  short* W3t  = W2t + 3072 * 256;          // (2048,256): qu|rq ^T — CONTIGUOUS
                                           //  after W2t (gemm23 requires it)
  short* C1   = (short*)(ws + 25 * MB);    // (4096,1536): kv_d|q_d|k_r
  short* C2   = (short*)(ws + 37 * MB);    // (4096,3072): k_c|v
  short* C3   = (short*)(ws + 61 * MB);    // (4096,2048): q_c|q_r
  short* Wo_t = (short*)(ws + 77 * MB);    // (2048,2048)
  short* q_f  = (short*)(ws + 85 * MB);    // (32,2048,128)
  short* k_f  = (short*)(ws + 101 * MB);
  short* v_t  = (short*)(ws + 117 * MB);   // (32,128,2048)
  short* y_b  = (short*)(ws + 133 * MB);   // (b,s,h,d)
  short*  partb = (short*)(ws + 0 * MB);   // overlay: 2048x64x128 bf16 (32 MB)
  float2* mlb   = (float2*)(ws + 32 * MB); // 1 MB

  dim3 blk(256);
  prep_all<<<dim3(16640), blk, 0, stream>>>(hs, Wkvd, Wqd, Wku, Wqu, Wvu, Wrk,
                                            Wrq, Wo, hs_b, W1t, W2t, W3t, Wo_t);

  gemm_bt<short><<<dim3(12, 32), blk, 0, stream>>>(hs_b, 2048, W1t, 2048, C1, 1536, 2048);
  gemm23<<<dim3(40, 32), blk, 0, stream>>>(C1, W2t, C2, C3);

  rope_vtrans<<<dim3(34816), blk, 0, stream>>>(C3, C2, C1, q_f, k_f, v_t);

  attn_split<<<dim3(1024), blk, 0, stream>>>(q_f, k_f, v_t, partb, mlb);
  attn_merge<<<dim3(1024), blk, 0, stream>>>(partb, mlb, y_b);

  gemm_bt<float><<<dim3(16, 32), blk, 0, stream>>>(y_b, 2048, Wo_t, 2048, out, 2048, 2048);
}

// Round 12
// 328.991 us; speedup vs baseline: 1.6618x; 1.0062x over previous
//
#include <hip/hip_runtime.h>
#include <hip/hip_bf16.h>
#include <math.h>

// ---------------------------------------------------------------------------
// MLA forward, bf16 MFMA.
// r12 = r11 + vtrans DELETED: gemm23's V region (bx 8..23) stores its
// accumulator directly into v_t (transposed) — each lane's acc[i][j] holds
// 4 consecutive-s values at fixed d, matching v_t[bh][d][s]'s contiguous
// dim, so the transpose is free in the epilogue. C2 shrinks to k_c (ld
// 1024); rope_pack reverts to a pure kernel. Saves 32MB of traffic.
// ROUND-11 LESSON: attn occupancy 2x'd (10.6->22.7%) with dur unchanged —
// attn is VALU/LDS-bound, not occupancy-bound; parked at ~85us.
// ROUND-9 LESSON: __threadfence on gfx950 invalidates per-XCD L2 — never
// fence inside an L2-locality-dependent kernel; separate merge kernel.
// ROUND-4 LESSON: never force min-waves launch_bounds (VGPR cap -> spill).
// ROUND-5 LESSON: extra split-K ways cost ~16MB partial traffic per way.
// ROUND-6/8 LESSON: audit overlay LIFETIMES against the full stream schedule.
// B=2 S=2048 H=2048 nh=16 hd=128 rd=64 L=256
// ---------------------------------------------------------------------------

typedef __attribute__((ext_vector_type(8))) short bf16x8;
typedef __attribute__((ext_vector_type(4))) float f32x4;
typedef unsigned int u32;

#define MFMA16(a, b, c) __builtin_amdgcn_mfma_f32_16x16x32_bf16(a, b, c, 0, 0, 0)

__device__ __forceinline__ short f2bs(float f) {
  __hip_bfloat16 h = __float2bfloat16(f);
  return *reinterpret_cast<short*>(&h);
}
__device__ __forceinline__ float bs2f(short s) {
  union { unsigned int u; float f; } v;
  v.u = ((unsigned int)(unsigned short)s) << 16;
  return v.f;
}
__device__ __forceinline__ u32 fbits(float f) {
  union { float f; u32 u; } v; v.f = f; return v.u;
}

__device__ __forceinline__ void async16(const void* g, void* l) {
  __builtin_amdgcn_global_load_lds(
      (const __attribute__((address_space(1))) u32*)(unsigned long long)g,
      (__attribute__((address_space(3))) u32*)(unsigned int)(unsigned long long)l,
      16, 0, 0);
}
__device__ __forceinline__ void wait_vm0() {
  __builtin_amdgcn_s_waitcnt(0x0f70);  // vmcnt(0) only
}

// ---------------- fused prep: cast hs + all weight transposes --------------
__device__ __forceinline__ void wtrans_tile(const float* __restrict__ W,
                                            short* __restrict__ Wt, int K, int N,
                                            int bx, int by, int tid) {
  __shared__ float t[32][33];
  int k0 = by * 32, n0 = bx * 32;
#pragma unroll
  for (int i = 0; i < 4; ++i) {
    int idx = tid + i * 256;
    int r = idx >> 5, c = idx & 31;
    t[r][c] = W[(size_t)(k0 + r) * N + n0 + c];
  }
  __syncthreads();
#pragma unroll
  for (int i = 0; i < 4; ++i) {
    int idx = tid + i * 256;
    int r = idx >> 5, c = idx & 31;
    Wt[(size_t)(n0 + r) * K + k0 + c] = f2bs(t[c][r]);
  }
}

__global__ __launch_bounds__(256) void prep_all(
    const float* __restrict__ hs, const float* __restrict__ Wkvd,
    const float* __restrict__ Wqd, const float* __restrict__ Wku,
    const float* __restrict__ Wqu, const float* __restrict__ Wvu,
    const float* __restrict__ Wrk, const float* __restrict__ Wrq,
    const float* __restrict__ Wo, short* __restrict__ hs_b,
    short* __restrict__ W1t, short* __restrict__ W2t,
    short* __restrict__ W3t, short* __restrict__ Wo_t) {
  const int b = blockIdx.x, tid = threadIdx.x;
  if (b < 8192) {
    int i = (b * 256 + tid) * 4;
    float4 v = *(const float4*)(hs + i);
    short4 o;
    o.x = f2bs(v.x); o.y = f2bs(v.y); o.z = f2bs(v.z); o.w = f2bs(v.w);
    *(short4*)(hs_b + i) = o;
  } else if (b < 8704) {
    int l = b - 8192; wtrans_tile(Wkvd, W1t, 2048, 256, l & 7, l >> 3, tid);
  } else if (b < 9216) {
    int l = b - 8704; wtrans_tile(Wqd, W1t + 256 * 2048, 2048, 256, l & 7, l >> 3, tid);
  } else if (b < 11264) {
    int l = b - 9216; wtrans_tile(Wrk, W1t + 512 * 2048, 2048, 1024, l & 31, l >> 5, tid);
  } else if (b < 11520) {
    int l = b - 11264; wtrans_tile(Wku, W2t, 256, 1024, l & 31, l >> 5, tid);
  } else if (b < 12032) {
    int l = b - 11520; wtrans_tile(Wvu, W2t + 1024 * 256, 256, 2048, l & 63, l >> 6, tid);
  } else if (b < 12288) {
    int l = b - 12032; wtrans_tile(Wqu, W3t, 256, 1024, l & 31, l >> 5, tid);
  } else if (b < 12544) {
    int l = b - 12288; wtrans_tile(Wrq, W3t + 1024 * 256, 256, 1024, l & 31, l >> 5, tid);
  } else {
    int l = b - 12544; wtrans_tile(Wo, Wo_t, 2048, 2048, l & 63, l >> 6, tid);
  }
}

// ---------------- bf16 MFMA GEMM, BK=64, swizzled staging: C = A @ Bt^T ----
__device__ __forceinline__ void cstore(float v, float* p) { *p = v; }
__device__ __forceinline__ void cstore(float v, short* p) { *p = f2bs(v); }

template <typename CT>
__global__ __launch_bounds__(256) void gemm_bt(const short* __restrict__ A, int lda,
                                               const short* __restrict__ Bt, int ldb,
                                               CT* __restrict__ C, int ldc, int K) {
  __shared__ short As[128 * 64];
  __shared__ short Bs[128 * 64];
  const int tid = threadIdx.x;
  const int wave = tid >> 6, lane = tid & 63;
  const int quad = lane >> 4, l15 = lane & 15;
  const int wm = wave & 1, wn = wave >> 1;
  const int row0 = blockIdx.y * 128, col0 = blockIdx.x * 128;
  const int sr = tid >> 3;                    // staging row 0..31 (+i*32)
  const int sc = ((tid & 7) ^ (sr & 7)) * 8;  // inverse-swizzled global chunk
  const short* Ag = A + (size_t)(row0 + sr) * lda + sc;
  const short* Bg = Bt + (size_t)(col0 + sr) * ldb + sc;
  const int rk = l15 & 7;                     // read-side XOR key (row&7)

  f32x4 acc[4][4];
#pragma unroll
  for (int i = 0; i < 4; ++i)
#pragma unroll
    for (int j = 0; j < 4; ++j) acc[i][j] = {0.f, 0.f, 0.f, 0.f};

  for (int k0 = 0; k0 < K; k0 += 64) {
    __syncthreads();
#pragma unroll
    for (int i = 0; i < 4; ++i) {
      async16(Ag + (size_t)(i * 32) * lda + k0, &As[i * 2048 + tid * 8]);
      async16(Bg + (size_t)(i * 32) * ldb + k0, &Bs[i * 2048 + tid * 8]);
    }
    wait_vm0();
    __syncthreads();
#pragma unroll
    for (int s = 0; s < 2; ++s) {
      bf16x8 af[4], bfr[4];
#pragma unroll
      for (int i = 0; i < 4; ++i) {
        af[i]  = *(const bf16x8*)&As[(wm * 64 + i * 16 + l15) * 64 +
                                     ((s * 4 + quad) ^ rk) * 8];
        bfr[i] = *(const bf16x8*)&Bs[(wn * 64 + i * 16 + l15) * 64 +
                                     ((s * 4 + quad) ^ rk) * 8];
      }
#pragma unroll
      for (int i = 0; i < 4; ++i)
#pragma unroll
        for (int j = 0; j < 4; ++j)
          acc[i][j] = MFMA16(af[i], bfr[j], acc[i][j]);
    }
  }
#pragma unroll
  for (int i = 0; i < 4; ++i)
#pragma unroll
    for (int j = 0; j < 4; ++j)
#pragma unroll
      for (int r = 0; r < 4; ++r) {
        int row = row0 + wm * 64 + i * 16 + quad * 4 + r;
        int col = col0 + wn * 64 + j * 16 + l15;
        cstore(acc[i][j][r], &C[(size_t)row * ldc + col]);
      }
}

// ---- fused gemm2+gemm3+vtrans, BK=64 --------------------------------------
// bx 0..7:   k_c -> C2 (4096 x 1024, ld 1024)
// bx 8..23:  v   -> v_t DIRECT transposed store (acc holds 4 consecutive s
//            at fixed d == v_t's contiguous dim; one h per bx)
// bx 24..39: q_c|q_r -> C3 (ld 2048)
// REQUIRES: W3t == W2t + 3072*256 (enforced in kernel_launch layout).
__global__ __launch_bounds__(256) void gemm23(const short* __restrict__ C1,
                                              const short* __restrict__ W2t,
                                              short* __restrict__ C2,
                                              short* __restrict__ C3,
                                              short* __restrict__ vt) {
  __shared__ short As[128 * 64];
  __shared__ short Bs[128 * 64];
  const int tid = threadIdx.x;
  const int wave = tid >> 6, lane = tid & 63;
  const int quad = lane >> 4, l15 = lane & 15;
  const int wm = wave & 1, wn = wave >> 1;
  const int bx = blockIdx.x;
  const short* A = bx < 24 ? C1 : C1 + 256;  // kv_d vs q_d columns of C1
  const int row0 = blockIdx.y * 128;
  const int sr = tid >> 3;
  const int sc = ((tid & 7) ^ (sr & 7)) * 8;
  const short* Ag = A + (size_t)(row0 + sr) * 1536 + sc;
  const short* Bg = W2t + (size_t)(bx * 128 + sr) * 256 + sc;  // W3t contiguous
  const int rk = l15 & 7;

  f32x4 acc[4][4];
#pragma unroll
  for (int i = 0; i < 4; ++i)
#pragma unroll
    for (int j = 0; j < 4; ++j) acc[i][j] = {0.f, 0.f, 0.f, 0.f};

  for (int k0 = 0; k0 < 256; k0 += 64) {
    __syncthreads();
#pragma unroll
    for (int i = 0; i < 4; ++i) {
      async16(Ag + (size_t)(i * 32) * 1536 + k0, &As[i * 2048 + tid * 8]);
      async16(Bg + (size_t)(i * 32) * 256 + k0, &Bs[i * 2048 + tid * 8]);
    }
    wait_vm0();
    __syncthreads();
#pragma unroll
    for (int s = 0; s < 2; ++s) {
      bf16x8 af[4], bfr[4];
#pragma unroll
      for (int i = 0; i < 4; ++i) {
        af[i]  = *(const bf16x8*)&As[(wm * 64 + i * 16 + l15) * 64 +
                                     ((s * 4 + quad) ^ rk) * 8];
        bfr[i] = *(const bf16x8*)&Bs[(wn * 64 + i * 16 + l15) * 64 +
                                     ((s * 4 + quad) ^ rk) * 8];
      }
#pragma unroll
      for (int i = 0; i < 4; ++i)
#pragma unroll
        for (int j = 0; j < 4; ++j)
          acc[i][j] = MFMA16(af[i], bfr[j], acc[i][j]);
    }
  }

  if (bx >= 8 && bx < 24) {
    // V: direct transposed store. Block rows are 128-aligned -> one b.
    const int b = row0 >> 11;
    const int s0 = row0 & 2047;
#pragma unroll
    for (int i = 0; i < 4; ++i)
#pragma unroll
      for (int j = 0; j < 4; ++j) {
        int vcol = (bx - 8) * 128 + wn * 64 + j * 16 + l15;  // 0..2047
        int h = vcol >> 7, d = vcol & 127;
        int s = s0 + wm * 64 + i * 16 + quad * 4;
        short4 o;
        o.x = f2bs(acc[i][j][0]); o.y = f2bs(acc[i][j][1]);
        o.z = f2bs(acc[i][j][2]); o.w = f2bs(acc[i][j][3]);
        *(short4*)&vt[((size_t)((b * 16 + h) * 128 + d)) * 2048 + s] = o;
      }
  } else {
    short* C = bx < 8 ? C2 : C3;
    const int ldc = bx < 8 ? 1024 : 2048;
    const int colbase = bx < 8 ? bx * 128 : (bx - 24) * 128;
#pragma unroll
    for (int i = 0; i < 4; ++i)
#pragma unroll
      for (int j = 0; j < 4; ++j)
#pragma unroll
        for (int r = 0; r < 4; ++r) {
          int row = row0 + wm * 64 + i * 16 + quad * 4 + r;
          int col = colbase + wn * 64 + j * 16 + l15;
          C[(size_t)row * ldc + col] = f2bs(acc[i][j][r]);
        }
  }
}

// ---------------- RoPE + concat + head-major pack (bf16) -------------------
// c2 now holds only k_c: (4096 x 1024), ld 1024.
__global__ __launch_bounds__(256) void rope_pack(
    const short* __restrict__ c3, const short* __restrict__ c2,
    const short* __restrict__ c1, short* __restrict__ qf,
    short* __restrict__ kf) {
  const float QSCALE = 0.08838834764831845f * 1.4426950408889634f;
  int idx = blockIdx.x * 256 + threadIdx.x;
  int m = idx >> 11;
  int col = idx & 2047;
  int h = col >> 7;
  int j = col & 127;
  int b = m >> 11, s = m & 2047;
  float oq, ok;
  if (j < 64) {
    oq = bs2f(c3[(size_t)m * 2048 + h * 64 + j]);
    ok = bs2f(c2[(size_t)m * 1024 + h * 64 + j]);
  } else {
    int jr = j - 64;
    int f = jr & 31;
    float ang = (float)s * __expf(-0.2878231366242557f * (float)f);
    float c = __cosf(ang), sn = __sinf(ang);
    size_t qb = (size_t)m * 2048 + 1024 + h * 64;
    size_t kb = (size_t)m * 1536 + 512 + h * 64;
    float xq = bs2f(c3[qb + jr]), xk = bs2f(c1[kb + jr]);
    float rq, rk;
    if (jr < 32) { rq = -bs2f(c3[qb + jr + 32]); rk = -bs2f(c1[kb + jr + 32]); }
    else         { rq =  bs2f(c3[qb + jr - 32]); rk =  bs2f(c1[kb + jr - 32]); }
    oq = fmaf(xq, c, rq * sn);
    ok = fmaf(xk, c, rk * sn);
  }
  size_t dst = (((size_t)b * 16 + h) * 2048 + s) * 128 + j;
  qf[dst] = f2bs(oq * QSCALE);
  kf[dst] = f2bs(ok);
}

// ---------------- 2-way split-K flash attention, QBLK=64 KVBLK=32 ----------
// grid 1024: bh = (lid&7)*4 + ((lid>>3)&3) (XCD-local), x = lid>>5 (0..31).
// pass0: (qt=x, half0); pass1: (qt=31-x, half1). 33 k-tiles per block.
// LDS 36KB -> 4 blocks/CU. Parked at ~85us (r11: occupancy-exonerated).
__global__ __launch_bounds__(256) void attn_split(const short* __restrict__ qf,
                                                  const short* __restrict__ kf,
                                                  const short* __restrict__ vt,
                                                  short* __restrict__ part,
                                                  float2* __restrict__ ml) {
  __shared__ short Ks[2][32 * 128];  // [kpos][d], granule-swizzled (16KB)
  __shared__ short Vs[2][128 * 32];  // [d][kpos], granule-swizzled (16KB)
  __shared__ short Pw[4][16 * 32];   // per-wave P^T, 2-bit XOR swz (4KB)
  const int lid = blockIdx.x;
  const int bh = (lid & 7) * 4 + ((lid >> 3) & 3);  // 4 bh per XCD
  const int x  = lid >> 5;                          // 0..31
  const int tid = threadIdx.x;
  const int wave = tid >> 6, lane = tid & 63;
  const int quad = lane >> 4, l15 = lane & 15;
  const int krow_l = tid >> 4;                      // 0..15
  const int kcol_sw = ((tid & 15) ^ krow_l) * 8;
  const int vrow_l = tid >> 2;                      // 0..63
  const int vcol_sw = ((tid & 3) ^ (vrow_l & 3) ^ ((vrow_l >> 2) & 3)) * 8;
  const short* kgB = kf + (((size_t)bh * 2048) + krow_l) * 128 + kcol_sw;
  const short* vgB = vt + ((size_t)bh * 128 + vrow_l) * 2048 + vcol_sw;
  const int pswz = l15 & 6;  // XOR on 4-short granule index bits 1..2

  for (int pass = 0; pass < 2; ++pass) {
    const int qt = pass ? 31 - x : x;       // 64-row q-tile index 0..31
    const int ks = pass ? qt + 1 : 0;       // half0 / half1 of causal range
    const int ke = pass ? 2 * (qt + 1) : x + 1;
    const int q0w = qt * 64 + wave * 16;

    bf16x8 qfr[4];
    {
      const short* qp = qf + (((size_t)bh * 2048) + q0w + l15) * 128;
#pragma unroll
      for (int kc = 0; kc < 4; ++kc)
        qfr[kc] = *(const bf16x8*)(qp + kc * 32 + quad * 8);
    }
    float m_i = -INFINITY;
    float l_i = 0.f;  // per-lane partial sum (reduced at pass end)
    f32x4 O[8];
#pragma unroll
    for (int dt = 0; dt < 8; ++dt) O[dt] = {0.f, 0.f, 0.f, 0.f};

    // prologue: stage first tile into buf 0 (2 async16 each per thread)
    {
      const short* kg = kgB + (size_t)ks * 32 * 128;
      const short* vg = vgB + ks * 32;
#pragma unroll
      for (int i = 0; i < 2; ++i) {
        async16(kg + (size_t)i * 16 * 128, &Ks[0][i * 2048 + tid * 8]);
        async16(vg + (size_t)i * 64 * 2048, &Vs[0][i * 2048 + tid * 8]);
      }
    }
    wait_vm0();
    __syncthreads();

    int cur = 0;
    for (int kt = ks; kt < ke; ++kt) {
      const int k0 = kt * 32;
      if (kt + 1 < ke) {  // DMA next tile into the other buffer (no barrier)
        const short* kg = kgB + (size_t)(kt + 1) * 32 * 128;
        const short* vg = vgB + (kt + 1) * 32;
#pragma unroll
        for (int i = 0; i < 2; ++i) {
          async16(kg + (size_t)i * 16 * 128, &Ks[cur ^ 1][i * 2048 + tid * 8]);
          async16(vg + (size_t)i * 64 * 2048, &Vs[cur ^ 1][i * 2048 + tid * 8]);
        }
      }

      // S^T = K @ Q^T  (m=kpos 32, n=qrow 16); lane col l15 = q-row
      f32x4 St[2];
#pragma unroll
      for (int j = 0; j < 2; ++j) St[j] = {0.f, 0.f, 0.f, 0.f};
      __builtin_amdgcn_s_setprio(1);
#pragma unroll
      for (int kc = 0; kc < 4; ++kc) {
        bf16x8 kb[2];
#pragma unroll
        for (int j = 0; j < 2; ++j)
          kb[j] = *(const bf16x8*)&Ks[cur][(j * 16 + l15) * 128 +
                                          (((kc * 4 + quad) ^ l15) & 15) * 8];
#pragma unroll
        for (int j = 0; j < 2; ++j)
          St[j] = MFMA16(kb[j], qfr[kc], St[j]);
      }
      __builtin_amdgcn_s_setprio(0);

      if (kt >= 2 * qt) {  // diagonal: causal mask
#pragma unroll
        for (int j = 0; j < 2; ++j)
#pragma unroll
          for (int r = 0; r < 4; ++r)
            if (k0 + j * 16 + quad * 4 + r > q0w + l15)
              St[j][r] = -INFINITY;
      }

      // online softmax: defer-max, per-lane trigger, per-lane partial l
      {
        float mt = -INFINITY;  // per-lane local max over 8 vals
#pragma unroll
        for (int j = 0; j < 2; ++j)
#pragma unroll
          for (int r = 0; r < 4; ++r) mt = fmaxf(mt, St[j][r]);
        if (!__all(mt <= m_i + 8.f)) {
          mt = fmaxf(mt, __shfl_xor(mt, 16));
          mt = fmaxf(mt, __shfl_xor(mt, 32));
          float mnew = fmaxf(m_i, mt);  // finite: trigger implies finite mt
          float a = __builtin_amdgcn_exp2f(m_i - mnew);  // -inf -> 0
          m_i = mnew;
          l_i *= a;
#pragma unroll
          for (int dt = 0; dt < 8; ++dt)
#pragma unroll
            for (int r = 0; r < 4; ++r) O[dt][r] *= a;
        }
        float ms = (m_i == -INFINITY) ? 0.f : m_i;
        float ps = 0.f;
#pragma unroll
        for (int j = 0; j < 2; ++j)
#pragma unroll
          for (int r = 0; r < 4; ++r) {
            float p = __builtin_amdgcn_exp2f(St[j][r] - ms);
            St[j][r] = p;
            ps += p;
          }
        l_i += ps;
      }

      // P^T (truncated bf16) -> per-wave LDS, 32 shorts/row, granule-XOR swz
      {
        int pr = l15;
#pragma unroll
        for (int j = 0; j < 2; ++j) {
          u32 u0 = (fbits(St[j][1]) & 0xffff0000u) | (fbits(St[j][0]) >> 16);
          u32 u1 = (fbits(St[j][3]) & 0xffff0000u) | (fbits(St[j][2]) >> 16);
          uint2 pk; pk.x = u0; pk.y = u1;
          int g = (j * 4 + quad) ^ pswz;  // logical granule j*4+quad
          *(uint2*)&Pw[wave][pr * 32 + g * 4] = pk;
        }
      }

      // O^T += V^T-frag @ P-frag (K=32: single k-chunk)
      __builtin_amdgcn_s_setprio(1);
      bf16x8 pa;
      {
        int g = (quad * 2) ^ pswz;  // logical granules 2q,2q+1 (pswz even)
        pa = *(const bf16x8*)&Pw[wave][l15 * 32 + g * 4];
      }
#pragma unroll
      for (int dt = 0; dt < 8; ++dt) {
        bf16x8 vb = *(const bf16x8*)&Vs[cur][(dt * 16 + l15) * 32 +
                                            ((quad ^ (l15 & 3) ^ ((l15 >> 2) & 3)) & 3) * 8];
        O[dt] = MFMA16(vb, pa, O[dt]);
      }
      __builtin_amdgcn_s_setprio(0);

      wait_vm0();       // next tile's DMA done (overlapped by compute above)
      __syncthreads();  // all waves done reading cur + all DMAs drained
      cur ^= 1;
    }

    // store partial O as bf16: [qrow 64][d 128]
    const int pidx = (bh * 32 + qt) * 2 + pass;
    short* pb = part + (size_t)pidx * 64 * 128;
    {
      int qrow = wave * 16 + l15;
#pragma unroll
      for (int dt = 0; dt < 8; ++dt) {
        short4 o;
        o.x = f2bs(O[dt][0]); o.y = f2bs(O[dt][1]);
        o.z = f2bs(O[dt][2]); o.w = f2bs(O[dt][3]);
        *(short4*)&pb[(size_t)qrow * 128 + dt * 16 + quad * 4] = o;
      }
    }
    // cross-quad reduce of per-lane l partials (all lanes execute shfls)
    float lr = l_i;
    lr += __shfl_xor(lr, 16);
    lr += __shfl_xor(lr, 32);
    if (quad == 0) {
      float2 v; v.x = m_i; v.y = lr;
      ml[pidx * 64 + wave * 16 + l15] = v;
    }
  }
}

// ---------------- merge two partials per 64-row q-tile ---------------------
// grid 1024, XCD-matched decode (lid%8 == bh>>2).
__global__ __launch_bounds__(256) void attn_merge(const short* __restrict__ part,
                                                  const float2* __restrict__ ml,
                                                  short* __restrict__ y) {
  const int l = blockIdx.x;
  const int bh = ((l & 7) << 2) | ((l >> 3) & 3);
  const int qt = (l >> 5) & 31;
  const int b = bh >> 4, h = bh & 15;
  const int row = threadIdx.x >> 2, d0 = (threadIdx.x & 3) * 32;
  const int p1 = (bh * 32 + qt) * 2, p2 = p1 + 1;
  float2 a = ml[p1 * 64 + row], c = ml[p2 * 64 + row];
  float m = fmaxf(a.x, c.x);
  float a1 = __builtin_amdgcn_exp2f(a.x - m);
  float a2 = __builtin_amdgcn_exp2f(c.x - m);
  float invl = 1.f / (a.y * a1 + c.y * a2);
  a1 *= invl; a2 *= invl;
  const short* s1 = part + ((size_t)p1 * 64 + row) * 128 + d0;
  const short* s2 = part + ((size_t)p2 * 64 + row) * 128 + d0;
  short* yp = y + (((size_t)b * 2048 + qt * 64 + row) * 16 + h) * 128 + d0;
#pragma unroll
  for (int j = 0; j < 8; ++j) {
    short4 v1 = *(const short4*)(s1 + j * 4);
    short4 v2 = *(const short4*)(s2 + j * 4);
    short4 o;
    o.x = f2bs(bs2f(v1.x) * a1 + bs2f(v2.x) * a2);
    o.y = f2bs(bs2f(v1.y) * a1 + bs2f(v2.y) * a2);
    o.z = f2bs(bs2f(v1.z) * a1 + bs2f(v2.z) * a2);
    o.w = f2bs(bs2f(v1.w) * a1 + bs2f(v2.w) * a2);
    *(short4*)(yp + j * 4) = o;
  }
}

extern "C" void kernel_launch(void* const* d_in, const int* in_sizes, int n_in,
                              void* d_out, int out_size, void* d_ws, size_t ws_size,
                              hipStream_t stream) {
  const float* hs   = (const float*)d_in[0];
  const float* Wkvd = (const float*)d_in[1];
  const float* Wqd  = (const float*)d_in[2];
  const float* Wku  = (const float*)d_in[3];
  const float* Wqu  = (const float*)d_in[4];
  const float* Wvu  = (const float*)d_in[5];
  const float* Wrk  = (const float*)d_in[6];
  const float* Wrq  = (const float*)d_in[7];
  const float* Wo   = (const float*)d_in[8];
  float* out = (float*)d_out;
  char* ws = (char*)d_ws;
  const size_t MB = 1024ull * 1024ull;

  short* hs_b = (short*)(ws + 0 * MB);     // 16 MB
  short* W1t  = (short*)(ws + 16 * MB);    // (1536,2048): kvd|qd|rk ^T
  short* W2t  = (short*)(ws + 22 * MB);    // (3072,256): ku|vu ^T
  short* W3t  = W2t + 3072 * 256;          // (2048,256): qu|rq ^T — CONTIGUOUS
                                           //  after W2t (gemm23 requires it)
  short* C1   = (short*)(ws + 25 * MB);    // (4096,1536): kv_d|q_d|k_r
  short* C2   = (short*)(ws + 37 * MB);    // (4096,1024): k_c only (8 MB)
  short* C3   = (short*)(ws + 61 * MB);    // (4096,2048): q_c|q_r
  short* Wo_t = (short*)(ws + 77 * MB);    // (2048,2048)
  short* q_f  = (short*)(ws + 85 * MB);    // (32,2048,128)
  short* k_f  = (short*)(ws + 101 * MB);
  short* v_t  = (short*)(ws + 117 * MB);   // (32,128,2048) — written by gemm23
  short* y_b  = (short*)(ws + 133 * MB);   // (b,s,h,d)
  short*  partb = (short*)(ws + 0 * MB);   // overlay: 2048x64x128 bf16 (32 MB)
  float2* mlb   = (float2*)(ws + 32 * MB); // 1 MB (inside dead C1 at attn time)

  dim3 blk(256);
  prep_all<<<dim3(16640), blk, 0, stream>>>(hs, Wkvd, Wqd, Wku, Wqu, Wvu, Wrk,
                                            Wrq, Wo, hs_b, W1t, W2t, W3t, Wo_t);

  gemm_bt<short><<<dim3(12, 32), blk, 0, stream>>>(hs_b, 2048, W1t, 2048, C1, 1536, 2048);
  gemm23<<<dim3(40, 32), blk, 0, stream>>>(C1, W2t, C2, C3, v_t);

  rope_pack<<<dim3(32768), blk, 0, stream>>>(C3, C2, C1, q_f, k_f);

  attn_split<<<dim3(1024), blk, 0, stream>>>(q_f, k_f, v_t, partb, mlb);
  attn_merge<<<dim3(1024), blk, 0, stream>>>(partb, mlb, y_b);

  gemm_bt<float><<<dim3(16, 32), blk, 0, stream>>>(y_b, 2048, Wo_t, 2048, out, 2048, 2048);
}

// Round 13
// 315.317 us; speedup vs baseline: 1.7338x; 1.0434x over previous
//
#include <hip/hip_runtime.h>
#include <hip/hip_bf16.h>
#include <math.h>

// ---------------------------------------------------------------------------
// MLA forward, bf16 MFMA.
// r13: rope_pack DELETED — RoPE applied in-register in GEMM epilogues.
// Fragment map puts rotation pairs (jr, jr+32) in the same lane (jj and
// jj+2), so gemm1's k_r blocks and gemm23's q_r blocks rotate in-register
// and store head-major directly. k_c/q_c also store direct. C2/C3 and
// C1's k_r third cease to exist (~64MB intermediate traffic gone).
// + XCD-aware block remap (T1) on all MFMA GEMMs (same-A-panel co-XCD).
// ROUND-12 LESSON: L2-resident intermediate traffic saves less than the
// HBM-bytes model suggests; fusing the PASS (launch + both copies) is the
// real win. ROUND-11: attn parked (~85us, VALU/LDS-bound, occupancy-proof).
// ROUND-9: no __threadfence in L2-dependent kernels. ROUND-4: no forced
// min-waves launch_bounds. ROUND-6/8: audit overlay lifetimes vs schedule.
// B=2 S=2048 H=2048 nh=16 hd=128 rd=64 L=256
// ---------------------------------------------------------------------------

typedef __attribute__((ext_vector_type(8))) short bf16x8;
typedef __attribute__((ext_vector_type(4))) float f32x4;
typedef unsigned int u32;

#define MFMA16(a, b, c) __builtin_amdgcn_mfma_f32_16x16x32_bf16(a, b, c, 0, 0, 0)

#define QSCALE_F (0.08838834764831845f * 1.4426950408889634f)
#define ROPE_EXP (-0.2878231366242557f)

__device__ __forceinline__ short f2bs(float f) {
  __hip_bfloat16 h = __float2bfloat16(f);
  return *reinterpret_cast<short*>(&h);
}
__device__ __forceinline__ float bs2f(short s) {
  union { unsigned int u; float f; } v;
  v.u = ((unsigned int)(unsigned short)s) << 16;
  return v.f;
}
__device__ __forceinline__ u32 fbits(float f) {
  union { float f; u32 u; } v; v.f = f; return v.u;
}

__device__ __forceinline__ void async16(const void* g, void* l) {
  __builtin_amdgcn_global_load_lds(
      (const __attribute__((address_space(1))) u32*)(unsigned long long)g,
      (__attribute__((address_space(3))) u32*)(unsigned int)(unsigned long long)l,
      16, 0, 0);
}
__device__ __forceinline__ void wait_vm0() {
  __builtin_amdgcn_s_waitcnt(0x0f70);  // vmcnt(0) only
}

// XCD-aware block remap: co-locate same-row-panel blocks on one XCD.
// Bijective for gridDim.y % 8 == 0 (ny=32 for all our GEMM grids).
__device__ __forceinline__ void xcd_remap(int& bx, int& by) {
  const int id = blockIdx.y * gridDim.x + blockIdx.x;
  const int nyp = gridDim.y >> 3;
  const int xcd = id & 7, t = id >> 3;
  by = xcd * nyp + (t % nyp);
  bx = t / nyp;
}

// ---------------- fused prep: cast hs + all weight transposes --------------
__device__ __forceinline__ void wtrans_tile(const float* __restrict__ W,
                                            short* __restrict__ Wt, int K, int N,
                                            int bx, int by, int tid) {
  __shared__ float t[32][33];
  int k0 = by * 32, n0 = bx * 32;
#pragma unroll
  for (int i = 0; i < 4; ++i) {
    int idx = tid + i * 256;
    int r = idx >> 5, c = idx & 31;
    t[r][c] = W[(size_t)(k0 + r) * N + n0 + c];
  }
  __syncthreads();
#pragma unroll
  for (int i = 0; i < 4; ++i) {
    int idx = tid + i * 256;
    int r = idx >> 5, c = idx & 31;
    Wt[(size_t)(n0 + r) * K + k0 + c] = f2bs(t[c][r]);
  }
}

__global__ __launch_bounds__(256) void prep_all(
    const float* __restrict__ hs, const float* __restrict__ Wkvd,
    const float* __restrict__ Wqd, const float* __restrict__ Wku,
    const float* __restrict__ Wqu, const float* __restrict__ Wvu,
    const float* __restrict__ Wrk, const float* __restrict__ Wrq,
    const float* __restrict__ Wo, short* __restrict__ hs_b,
    short* __restrict__ W1t, short* __restrict__ W2t,
    short* __restrict__ W3t, short* __restrict__ Wo_t) {
  const int b = blockIdx.x, tid = threadIdx.x;
  if (b < 8192) {
    int i = (b * 256 + tid) * 4;
    float4 v = *(const float4*)(hs + i);
    short4 o;
    o.x = f2bs(v.x); o.y = f2bs(v.y); o.z = f2bs(v.z); o.w = f2bs(v.w);
    *(short4*)(hs_b + i) = o;
  } else if (b < 8704) {
    int l = b - 8192; wtrans_tile(Wkvd, W1t, 2048, 256, l & 7, l >> 3, tid);
  } else if (b < 9216) {
    int l = b - 8704; wtrans_tile(Wqd, W1t + 256 * 2048, 2048, 256, l & 7, l >> 3, tid);
  } else if (b < 11264) {
    int l = b - 9216; wtrans_tile(Wrk, W1t + 512 * 2048, 2048, 1024, l & 31, l >> 5, tid);
  } else if (b < 11520) {
    int l = b - 11264; wtrans_tile(Wku, W2t, 256, 1024, l & 31, l >> 5, tid);
  } else if (b < 12032) {
    int l = b - 11520; wtrans_tile(Wvu, W2t + 1024 * 256, 256, 2048, l & 63, l >> 6, tid);
  } else if (b < 12288) {
    int l = b - 12032; wtrans_tile(Wqu, W3t, 256, 1024, l & 31, l >> 5, tid);
  } else if (b < 12544) {
    int l = b - 12288; wtrans_tile(Wrq, W3t + 1024 * 256, 256, 1024, l & 31, l >> 5, tid);
  } else {
    int l = b - 12544; wtrans_tile(Wo, Wo_t, 2048, 2048, l & 63, l >> 6, tid);
  }
}

// ---------------- bf16 MFMA GEMM, BK=64, swizzled staging (Wo gemm) --------
__device__ __forceinline__ void cstore(float v, float* p) { *p = v; }
__device__ __forceinline__ void cstore(float v, short* p) { *p = f2bs(v); }

template <typename CT>
__global__ __launch_bounds__(256) void gemm_bt(const short* __restrict__ A, int lda,
                                               const short* __restrict__ Bt, int ldb,
                                               CT* __restrict__ C, int ldc, int K) {
  __shared__ short As[128 * 64];
  __shared__ short Bs[128 * 64];
  const int tid = threadIdx.x;
  const int wave = tid >> 6, lane = tid & 63;
  const int quad = lane >> 4, l15 = lane & 15;
  const int wm = wave & 1, wn = wave >> 1;
  int bx, by; xcd_remap(bx, by);
  const int row0 = by * 128, col0 = bx * 128;
  const int sr = tid >> 3;
  const int sc = ((tid & 7) ^ (sr & 7)) * 8;
  const short* Ag = A + (size_t)(row0 + sr) * lda + sc;
  const short* Bg = Bt + (size_t)(col0 + sr) * ldb + sc;
  const int rk = l15 & 7;

  f32x4 acc[4][4];
#pragma unroll
  for (int i = 0; i < 4; ++i)
#pragma unroll
    for (int j = 0; j < 4; ++j) acc[i][j] = {0.f, 0.f, 0.f, 0.f};

  for (int k0 = 0; k0 < K; k0 += 64) {
    __syncthreads();
#pragma unroll
    for (int i = 0; i < 4; ++i) {
      async16(Ag + (size_t)(i * 32) * lda + k0, &As[i * 2048 + tid * 8]);
      async16(Bg + (size_t)(i * 32) * ldb + k0, &Bs[i * 2048 + tid * 8]);
    }
    wait_vm0();
    __syncthreads();
#pragma unroll
    for (int s = 0; s < 2; ++s) {
      bf16x8 af[4], bfr[4];
#pragma unroll
      for (int i = 0; i < 4; ++i) {
        af[i]  = *(const bf16x8*)&As[(wm * 64 + i * 16 + l15) * 64 +
                                     ((s * 4 + quad) ^ rk) * 8];
        bfr[i] = *(const bf16x8*)&Bs[(wn * 64 + i * 16 + l15) * 64 +
                                     ((s * 4 + quad) ^ rk) * 8];
      }
#pragma unroll
      for (int i = 0; i < 4; ++i)
#pragma unroll
        for (int j = 0; j < 4; ++j)
          acc[i][j] = MFMA16(af[i], bfr[j], acc[i][j]);
    }
  }
#pragma unroll
  for (int i = 0; i < 4; ++i)
#pragma unroll
    for (int j = 0; j < 4; ++j)
#pragma unroll
      for (int r = 0; r < 4; ++r) {
        int row = row0 + wm * 64 + i * 16 + quad * 4 + r;
        int col = col0 + wn * 64 + j * 16 + l15;
        cstore(acc[i][j][r], &C[(size_t)row * ldc + col]);
      }
}

// ---- gemm1k: C1[kvd|qd] + in-register RoPE for k_r -> k_f[64:] ------------
// A=hs_b (ld 2048), Bt=W1t (ld 2048), K=2048, grid (12,32).
// bx 0..3 : cols 0..511 (kv_d|q_d) -> C1 (ld 512)
// bx 4..11: cols 512..1535 (k_r, h*64+jr) -> RoPE -> k_f[(b,h,s)][64+jr]
// Lane holds both rotation halves: jj and jj+2 are jr and jr+32.
__global__ __launch_bounds__(256) void gemm1k(const short* __restrict__ A,
                                              const short* __restrict__ Bt,
                                              short* __restrict__ C1,
                                              short* __restrict__ kf) {
  __shared__ short As[128 * 64];
  __shared__ short Bs[128 * 64];
  const int tid = threadIdx.x;
  const int wave = tid >> 6, lane = tid & 63;
  const int quad = lane >> 4, l15 = lane & 15;
  const int wm = wave & 1, wn = wave >> 1;
  int bx, by; xcd_remap(bx, by);
  const int row0 = by * 128, col0 = bx * 128;
  const int sr = tid >> 3;
  const int sc = ((tid & 7) ^ (sr & 7)) * 8;
  const short* Ag = A + (size_t)(row0 + sr) * 2048 + sc;
  const short* Bg = Bt + (size_t)(col0 + sr) * 2048 + sc;
  const int rk = l15 & 7;

  f32x4 acc[4][4];
#pragma unroll
  for (int i = 0; i < 4; ++i)
#pragma unroll
    for (int j = 0; j < 4; ++j) acc[i][j] = {0.f, 0.f, 0.f, 0.f};

  for (int k0 = 0; k0 < 2048; k0 += 64) {
    __syncthreads();
#pragma unroll
    for (int i = 0; i < 4; ++i) {
      async16(Ag + (size_t)(i * 32) * 2048 + k0, &As[i * 2048 + tid * 8]);
      async16(Bg + (size_t)(i * 32) * 2048 + k0, &Bs[i * 2048 + tid * 8]);
    }
    wait_vm0();
    __syncthreads();
#pragma unroll
    for (int s = 0; s < 2; ++s) {
      bf16x8 af[4], bfr[4];
#pragma unroll
      for (int i = 0; i < 4; ++i) {
        af[i]  = *(const bf16x8*)&As[(wm * 64 + i * 16 + l15) * 64 +
                                     ((s * 4 + quad) ^ rk) * 8];
        bfr[i] = *(const bf16x8*)&Bs[(wn * 64 + i * 16 + l15) * 64 +
                                     ((s * 4 + quad) ^ rk) * 8];
      }
#pragma unroll
      for (int i = 0; i < 4; ++i)
#pragma unroll
        for (int j = 0; j < 4; ++j)
          acc[i][j] = MFMA16(af[i], bfr[j], acc[i][j]);
    }
  }

  if (bx < 4) {
#pragma unroll
    for (int i = 0; i < 4; ++i)
#pragma unroll
      for (int jj = 0; jj < 4; ++jj)
#pragma unroll
        for (int r = 0; r < 4; ++r) {
          int row = row0 + wm * 64 + i * 16 + quad * 4 + r;
          int col = col0 + wn * 64 + jj * 16 + l15;
          C1[(size_t)row * 512 + col] = f2bs(acc[i][jj][r]);
        }
  } else {
    const int colb = (bx - 4) * 128 + wn * 64 + l15;  // k_r col, jj=0
    const int h = colb >> 6;                          // constant over jj
    const float ef0 = __expf(ROPE_EXP * (float)l15);
    const float ef1 = __expf(ROPE_EXP * (float)(l15 + 16));
#pragma unroll
    for (int i = 0; i < 4; ++i)
#pragma unroll
      for (int r = 0; r < 4; ++r) {
        int row = row0 + wm * 64 + i * 16 + quad * 4 + r;
        int s = row & 2047, b = row >> 11;
        float fs = (float)s;
        float a0 = fs * ef0, a1 = fs * ef1;
        float c0 = __cosf(a0), s0 = __sinf(a0);
        float c1 = __cosf(a1), s1 = __sinf(a1);
        // jr<32: x*c - x_hi*s ; jr>=32: x*c + x_lo*s
        float o0 = acc[i][0][r] * c0 - acc[i][2][r] * s0;
        float o2 = acc[i][2][r] * c0 + acc[i][0][r] * s0;
        float o1 = acc[i][1][r] * c1 - acc[i][3][r] * s1;
        float o3 = acc[i][3][r] * c1 + acc[i][1][r] * s1;
        short* kp = kf + (((size_t)(b * 16 + h) * 2048 + s) * 128 + 64 + l15);
        kp[0]  = f2bs(o0);
        kp[16] = f2bs(o1);
        kp[32] = f2bs(o2);
        kp[48] = f2bs(o3);
      }
  }
}

// ---- gemm23: k_c->kf, v->vt, q_c->qf, q_r RoPE->qf ------------------------
// A = C1 (ld 512): bx<24 kv_d (cols 0..255), bx>=24 q_d (+256). K=256.
// B rows (W2t|W3t contig): bx 0..7 ku, 8..23 vu, 24..31 qu, 32..39 rq.
// REQUIRES: W3t == W2t + 3072*256 (enforced in kernel_launch layout).
__global__ __launch_bounds__(256) void gemm23(const short* __restrict__ C1,
                                              const short* __restrict__ W2t,
                                              short* __restrict__ qf,
                                              short* __restrict__ kf,
                                              short* __restrict__ vt) {
  __shared__ short As[128 * 64];
  __shared__ short Bs[128 * 64];
  const int tid = threadIdx.x;
  const int wave = tid >> 6, lane = tid & 63;
  const int quad = lane >> 4, l15 = lane & 15;
  const int wm = wave & 1, wn = wave >> 1;
  int bx, by; xcd_remap(bx, by);
  const short* A = bx < 24 ? C1 : C1 + 256;  // kv_d vs q_d columns
  const int row0 = by * 128;
  const int sr = tid >> 3;
  const int sc = ((tid & 7) ^ (sr & 7)) * 8;
  const short* Ag = A + (size_t)(row0 + sr) * 512 + sc;
  const short* Bg = W2t + (size_t)(bx * 128 + sr) * 256 + sc;  // W3t contiguous
  const int rk = l15 & 7;

  f32x4 acc[4][4];
#pragma unroll
  for (int i = 0; i < 4; ++i)
#pragma unroll
    for (int j = 0; j < 4; ++j) acc[i][j] = {0.f, 0.f, 0.f, 0.f};

  for (int k0 = 0; k0 < 256; k0 += 64) {
    __syncthreads();
#pragma unroll
    for (int i = 0; i < 4; ++i) {
      async16(Ag + (size_t)(i * 32) * 512 + k0, &As[i * 2048 + tid * 8]);
      async16(Bg + (size_t)(i * 32) * 256 + k0, &Bs[i * 2048 + tid * 8]);
    }
    wait_vm0();
    __syncthreads();
#pragma unroll
    for (int s = 0; s < 2; ++s) {
      bf16x8 af[4], bfr[4];
#pragma unroll
      for (int i = 0; i < 4; ++i) {
        af[i]  = *(const bf16x8*)&As[(wm * 64 + i * 16 + l15) * 64 +
                                     ((s * 4 + quad) ^ rk) * 8];
        bfr[i] = *(const bf16x8*)&Bs[(wn * 64 + i * 16 + l15) * 64 +
                                     ((s * 4 + quad) ^ rk) * 8];
      }
#pragma unroll
      for (int i = 0; i < 4; ++i)
#pragma unroll
        for (int j = 0; j < 4; ++j)
          acc[i][j] = MFMA16(af[i], bfr[j], acc[i][j]);
    }
  }

  if (bx < 8) {
    // k_c -> kf[..][j<64]. colb&63 == l15; h constant over jj.
    const int colb = bx * 128 + wn * 64 + l15;
    const int h = colb >> 6;
#pragma unroll
    for (int i = 0; i < 4; ++i)
#pragma unroll
      for (int r = 0; r < 4; ++r) {
        int row = row0 + wm * 64 + i * 16 + quad * 4 + r;
        int s = row & 2047, b = row >> 11;
        short* kp = kf + (((size_t)(b * 16 + h) * 2048 + s) * 128 + l15);
#pragma unroll
        for (int jj = 0; jj < 4; ++jj) kp[jj * 16] = f2bs(acc[i][jj][r]);
      }
  } else if (bx < 24) {
    // v -> v_t direct transposed store (r12-verified).
    const int b = row0 >> 11;
    const int s0 = row0 & 2047;
#pragma unroll
    for (int i = 0; i < 4; ++i)
#pragma unroll
      for (int jj = 0; jj < 4; ++jj) {
        int vcol = (bx - 8) * 128 + wn * 64 + jj * 16 + l15;  // 0..2047
        int h = vcol >> 7, d = vcol & 127;
        int s = s0 + wm * 64 + i * 16 + quad * 4;
        short4 o;
        o.x = f2bs(acc[i][jj][0]); o.y = f2bs(acc[i][jj][1]);
        o.z = f2bs(acc[i][jj][2]); o.w = f2bs(acc[i][jj][3]);
        *(short4*)&vt[((size_t)((b * 16 + h) * 128 + d)) * 2048 + s] = o;
      }
  } else if (bx < 32) {
    // q_c * QSCALE -> qf[..][j<64].
    const int colb = (bx - 24) * 128 + wn * 64 + l15;
    const int h = colb >> 6;
#pragma unroll
    for (int i = 0; i < 4; ++i)
#pragma unroll
      for (int r = 0; r < 4; ++r) {
        int row = row0 + wm * 64 + i * 16 + quad * 4 + r;
        int s = row & 2047, b = row >> 11;
        short* qp = qf + (((size_t)(b * 16 + h) * 2048 + s) * 128 + l15);
#pragma unroll
        for (int jj = 0; jj < 4; ++jj) qp[jj * 16] = f2bs(acc[i][jj][r] * QSCALE_F);
      }
  } else {
    // q_r RoPE * QSCALE -> qf[..][64+jr].
    const int colb = (bx - 32) * 128 + wn * 64 + l15;
    const int h = colb >> 6;
    const float ef0 = __expf(ROPE_EXP * (float)l15);
    const float ef1 = __expf(ROPE_EXP * (float)(l15 + 16));
#pragma unroll
    for (int i = 0; i < 4; ++i)
#pragma unroll
      for (int r = 0; r < 4; ++r) {
        int row = row0 + wm * 64 + i * 16 + quad * 4 + r;
        int s = row & 2047, b = row >> 11;
        float fs = (float)s;
        float a0 = fs * ef0, a1 = fs * ef1;
        float c0 = __cosf(a0), s0 = __sinf(a0);
        float c1 = __cosf(a1), s1 = __sinf(a1);
        float o0 = (acc[i][0][r] * c0 - acc[i][2][r] * s0) * QSCALE_F;
        float o2 = (acc[i][2][r] * c0 + acc[i][0][r] * s0) * QSCALE_F;
        float o1 = (acc[i][1][r] * c1 - acc[i][3][r] * s1) * QSCALE_F;
        float o3 = (acc[i][3][r] * c1 + acc[i][1][r] * s1) * QSCALE_F;
        short* qp = qf + (((size_t)(b * 16 + h) * 2048 + s) * 128 + 64 + l15);
        qp[0]  = f2bs(o0);
        qp[16] = f2bs(o1);
        qp[32] = f2bs(o2);
        qp[48] = f2bs(o3);
      }
  }
}

// ---------------- 2-way split-K flash attention, QBLK=64 KVBLK=32 ----------
// (r12 verbatim — parked at ~85us; occupancy-exonerated in r11.)
__global__ __launch_bounds__(256) void attn_split(const short* __restrict__ qf,
                                                  const short* __restrict__ kf,
                                                  const short* __restrict__ vt,
                                                  short* __restrict__ part,
                                                  float2* __restrict__ ml) {
  __shared__ short Ks[2][32 * 128];  // [kpos][d], granule-swizzled (16KB)
  __shared__ short Vs[2][128 * 32];  // [d][kpos], granule-swizzled (16KB)
  __shared__ short Pw[4][16 * 32];   // per-wave P^T, 2-bit XOR swz (4KB)
  const int lid = blockIdx.x;
  const int bh = (lid & 7) * 4 + ((lid >> 3) & 3);  // 4 bh per XCD
  const int x  = lid >> 5;                          // 0..31
  const int tid = threadIdx.x;
  const int wave = tid >> 6, lane = tid & 63;
  const int quad = lane >> 4, l15 = lane & 15;
  const int krow_l = tid >> 4;                      // 0..15
  const int kcol_sw = ((tid & 15) ^ krow_l) * 8;
  const int vrow_l = tid >> 2;                      // 0..63
  const int vcol_sw = ((tid & 3) ^ (vrow_l & 3) ^ ((vrow_l >> 2) & 3)) * 8;
  const short* kgB = kf + (((size_t)bh * 2048) + krow_l) * 128 + kcol_sw;
  const short* vgB = vt + ((size_t)bh * 128 + vrow_l) * 2048 + vcol_sw;
  const int pswz = l15 & 6;  // XOR on 4-short granule index bits 1..2

  for (int pass = 0; pass < 2; ++pass) {
    const int qt = pass ? 31 - x : x;       // 64-row q-tile index 0..31
    const int ks = pass ? qt + 1 : 0;       // half0 / half1 of causal range
    const int ke = pass ? 2 * (qt + 1) : x + 1;
    const int q0w = qt * 64 + wave * 16;

    bf16x8 qfr[4];
    {
      const short* qp = qf + (((size_t)bh * 2048) + q0w + l15) * 128;
#pragma unroll
      for (int kc = 0; kc < 4; ++kc)
        qfr[kc] = *(const bf16x8*)(qp + kc * 32 + quad * 8);
    }
    float m_i = -INFINITY;
    float l_i = 0.f;  // per-lane partial sum (reduced at pass end)
    f32x4 O[8];
#pragma unroll
    for (int dt = 0; dt < 8; ++dt) O[dt] = {0.f, 0.f, 0.f, 0.f};

    // prologue: stage first tile into buf 0 (2 async16 each per thread)
    {
      const short* kg = kgB + (size_t)ks * 32 * 128;
      const short* vg = vgB + ks * 32;
#pragma unroll
      for (int i = 0; i < 2; ++i) {
        async16(kg + (size_t)i * 16 * 128, &Ks[0][i * 2048 + tid * 8]);
        async16(vg + (size_t)i * 64 * 2048, &Vs[0][i * 2048 + tid * 8]);
      }
    }
    wait_vm0();
    __syncthreads();

    int cur = 0;
    for (int kt = ks; kt < ke; ++kt) {
      const int k0 = kt * 32;
      if (kt + 1 < ke) {  // DMA next tile into the other buffer (no barrier)
        const short* kg = kgB + (size_t)(kt + 1) * 32 * 128;
        const short* vg = vgB + (kt + 1) * 32;
#pragma unroll
        for (int i = 0; i < 2; ++i) {
          async16(kg + (size_t)i * 16 * 128, &Ks[cur ^ 1][i * 2048 + tid * 8]);
          async16(vg + (size_t)i * 64 * 2048, &Vs[cur ^ 1][i * 2048 + tid * 8]);
        }
      }

      // S^T = K @ Q^T  (m=kpos 32, n=qrow 16); lane col l15 = q-row
      f32x4 St[2];
#pragma unroll
      for (int j = 0; j < 2; ++j) St[j] = {0.f, 0.f, 0.f, 0.f};
      __builtin_amdgcn_s_setprio(1);
#pragma unroll
      for (int kc = 0; kc < 4; ++kc) {
        bf16x8 kb[2];
#pragma unroll
        for (int j = 0; j < 2; ++j)
          kb[j] = *(const bf16x8*)&Ks[cur][(j * 16 + l15) * 128 +
                                          (((kc * 4 + quad) ^ l15) & 15) * 8];
#pragma unroll
        for (int j = 0; j < 2; ++j)
          St[j] = MFMA16(kb[j], qfr[kc], St[j]);
      }
      __builtin_amdgcn_s_setprio(0);

      if (kt >= 2 * qt) {  // diagonal: causal mask
#pragma unroll
        for (int j = 0; j < 2; ++j)
#pragma unroll
          for (int r = 0; r < 4; ++r)
            if (k0 + j * 16 + quad * 4 + r > q0w + l15)
              St[j][r] = -INFINITY;
      }

      // online softmax: defer-max, per-lane trigger, per-lane partial l
      {
        float mt = -INFINITY;  // per-lane local max over 8 vals
#pragma unroll
        for (int j = 0; j < 2; ++j)
#pragma unroll
          for (int r = 0; r < 4; ++r) mt = fmaxf(mt, St[j][r]);
        if (!__all(mt <= m_i + 8.f)) {
          mt = fmaxf(mt, __shfl_xor(mt, 16));
          mt = fmaxf(mt, __shfl_xor(mt, 32));
          float mnew = fmaxf(m_i, mt);  // finite: trigger implies finite mt
          float a = __builtin_amdgcn_exp2f(m_i - mnew);  // -inf -> 0
          m_i = mnew;
          l_i *= a;
#pragma unroll
          for (int dt = 0; dt < 8; ++dt)
#pragma unroll
            for (int r = 0; r < 4; ++r) O[dt][r] *= a;
        }
        float ms = (m_i == -INFINITY) ? 0.f : m_i;
        float ps = 0.f;
#pragma unroll
        for (int j = 0; j < 2; ++j)
#pragma unroll
          for (int r = 0; r < 4; ++r) {
            float p = __builtin_amdgcn_exp2f(St[j][r] - ms);
            St[j][r] = p;
            ps += p;
          }
        l_i += ps;
      }

      // P^T (truncated bf16) -> per-wave LDS, 32 shorts/row, granule-XOR swz
      {
        int pr = l15;
#pragma unroll
        for (int j = 0; j < 2; ++j) {
          u32 u0 = (fbits(St[j][1]) & 0xffff0000u) | (fbits(St[j][0]) >> 16);
          u32 u1 = (fbits(St[j][3]) & 0xffff0000u) | (fbits(St[j][2]) >> 16);
          uint2 pk; pk.x = u0; pk.y = u1;
          int g = (j * 4 + quad) ^ pswz;  // logical granule j*4+quad
          *(uint2*)&Pw[wave][pr * 32 + g * 4] = pk;
        }
      }

      // O^T += V^T-frag @ P-frag (K=32: single k-chunk)
      __builtin_amdgcn_s_setprio(1);
      bf16x8 pa;
      {
        int g = (quad * 2) ^ pswz;  // logical granules 2q,2q+1 (pswz even)
        pa = *(const bf16x8*)&Pw[wave][l15 * 32 + g * 4];
      }
#pragma unroll
      for (int dt = 0; dt < 8; ++dt) {
        bf16x8 vb = *(const bf16x8*)&Vs[cur][(dt * 16 + l15) * 32 +
                                            ((quad ^ (l15 & 3) ^ ((l15 >> 2) & 3)) & 3) * 8];
        O[dt] = MFMA16(vb, pa, O[dt]);
      }
      __builtin_amdgcn_s_setprio(0);

      wait_vm0();       // next tile's DMA done (overlapped by compute above)
      __syncthreads();  // all waves done reading cur + all DMAs drained
      cur ^= 1;
    }

    // store partial O as bf16: [qrow 64][d 128]
    const int pidx = (bh * 32 + qt) * 2 + pass;
    short* pb = part + (size_t)pidx * 64 * 128;
    {
      int qrow = wave * 16 + l15;
#pragma unroll
      for (int dt = 0; dt < 8; ++dt) {
        short4 o;
        o.x = f2bs(O[dt][0]); o.y = f2bs(O[dt][1]);
        o.z = f2bs(O[dt][2]); o.w = f2bs(O[dt][3]);
        *(short4*)&pb[(size_t)qrow * 128 + dt * 16 + quad * 4] = o;
      }
    }
    // cross-quad reduce of per-lane l partials (all lanes execute shfls)
    float lr = l_i;
    lr += __shfl_xor(lr, 16);
    lr += __shfl_xor(lr, 32);
    if (quad == 0) {
      float2 v; v.x = m_i; v.y = lr;
      ml[pidx * 64 + wave * 16 + l15] = v;
    }
  }
}

// ---------------- merge two partials per 64-row q-tile ---------------------
// grid 1024, XCD-matched decode (lid%8 == bh>>2).
__global__ __launch_bounds__(256) void attn_merge(const short* __restrict__ part,
                                                  const float2* __restrict__ ml,
                                                  short* __restrict__ y) {
  const int l = blockIdx.x;
  const int bh = ((l & 7) << 2) | ((l >> 3) & 3);
  const int qt = (l >> 5) & 31;
  const int b = bh >> 4, h = bh & 15;
  const int row = threadIdx.x >> 2, d0 = (threadIdx.x & 3) * 32;
  const int p1 = (bh * 32 + qt) * 2, p2 = p1 + 1;
  float2 a = ml[p1 * 64 + row], c = ml[p2 * 64 + row];
  float m = fmaxf(a.x, c.x);
  float a1 = __builtin_amdgcn_exp2f(a.x - m);
  float a2 = __builtin_amdgcn_exp2f(c.x - m);
  float invl = 1.f / (a.y * a1 + c.y * a2);
  a1 *= invl; a2 *= invl;
  const short* s1 = part + ((size_t)p1 * 64 + row) * 128 + d0;
  const short* s2 = part + ((size_t)p2 * 64 + row) * 128 + d0;
  short* yp = y + (((size_t)b * 2048 + qt * 64 + row) * 16 + h) * 128 + d0;
#pragma unroll
  for (int j = 0; j < 8; ++j) {
    short4 v1 = *(const short4*)(s1 + j * 4);
    short4 v2 = *(const short4*)(s2 + j * 4);
    short4 o;
    o.x = f2bs(bs2f(v1.x) * a1 + bs2f(v2.x) * a2);
    o.y = f2bs(bs2f(v1.y) * a1 + bs2f(v2.y) * a2);
    o.z = f2bs(bs2f(v1.z) * a1 + bs2f(v2.z) * a2);
    o.w = f2bs(bs2f(v1.w) * a1 + bs2f(v2.w) * a2);
    *(short4*)(yp + j * 4) = o;
  }
}

extern "C" void kernel_launch(void* const* d_in, const int* in_sizes, int n_in,
                              void* d_out, int out_size, void* d_ws, size_t ws_size,
                              hipStream_t stream) {
  const float* hs   = (const float*)d_in[0];
  const float* Wkvd = (const float*)d_in[1];
  const float* Wqd  = (const float*)d_in[2];
  const float* Wku  = (const float*)d_in[3];
  const float* Wqu  = (const float*)d_in[4];
  const float* Wvu  = (const float*)d_in[5];
  const float* Wrk  = (const float*)d_in[6];
  const float* Wrq  = (const float*)d_in[7];
  const float* Wo   = (const float*)d_in[8];
  float* out = (float*)d_out;
  char* ws = (char*)d_ws;
  const size_t MB = 1024ull * 1024ull;

  short* hs_b = (short*)(ws + 0 * MB);     // 16 MB
  short* W1t  = (short*)(ws + 16 * MB);    // (1536,2048): kvd|qd|rk ^T
  short* W2t  = (short*)(ws + 22 * MB);    // (3072,256): ku|vu ^T
  short* W3t  = W2t + 3072 * 256;          // (2048,256): qu|rq ^T — CONTIGUOUS
                                           //  after W2t (gemm23 requires it)
  short* C1   = (short*)(ws + 25 * MB);    // (4096,512): kv_d|q_d (4 MB)
  short* Wo_t = (short*)(ws + 77 * MB);    // (2048,2048)
  short* q_f  = (short*)(ws + 85 * MB);    // (32,2048,128)
  short* k_f  = (short*)(ws + 101 * MB);   // j<64 by gemm23, j>=64 by gemm1k
  short* v_t  = (short*)(ws + 117 * MB);   // (32,128,2048) — by gemm23
  short* y_b  = (short*)(ws + 133 * MB);   // (b,s,h,d)
  short*  partb = (short*)(ws + 0 * MB);   // overlay: 2048x64x128 bf16 (32 MB)
  float2* mlb   = (float2*)(ws + 32 * MB); // 1 MB (dead region at attn time)

  dim3 blk(256);
  prep_all<<<dim3(16640), blk, 0, stream>>>(hs, Wkvd, Wqd, Wku, Wqu, Wvu, Wrk,
                                            Wrq, Wo, hs_b, W1t, W2t, W3t, Wo_t);

  gemm1k<<<dim3(12, 32), blk, 0, stream>>>(hs_b, W1t, C1, k_f);
  gemm23<<<dim3(40, 32), blk, 0, stream>>>(C1, W2t, q_f, k_f, v_t);

  attn_split<<<dim3(1024), blk, 0, stream>>>(q_f, k_f, v_t, partb, mlb);
  attn_merge<<<dim3(1024), blk, 0, stream>>>(partb, mlb, y_b);

  gemm_bt<float><<<dim3(16, 32), blk, 0, stream>>>(y_b, 2048, Wo_t, 2048, out, 2048, 2048);
}

// Round 14
// 288.252 us; speedup vs baseline: 1.8966x; 1.0939x over previous
//
#include <hip/hip_runtime.h>
#include <hip/hip_bf16.h>
#include <math.h>

// ---------------------------------------------------------------------------
// MLA forward, bf16 MFMA.
// r14 = r13 + GEMM double-buffer: all three MFMA GEMMs move from the serial
// {barrier, stage, vmcnt0, barrier, compute} schedule to the attn-proven
// {issue next-tile DMA, compute current, vmcnt0, ONE barrier} loop. Our
// GEMMs run at 1.5-2 blocks/CU (grid-limited) so there is no co-resident
// wave overlap to hide the drain — explicit dbuf hides DMA under compute.
// LDS 32->64KB (2 blocks/CU cap is moot at these grids). setprio on MFMA.
// ROUND-13: RoPE fused into GEMM epilogues (rope_pack deleted).
// ROUND-11: attn parked (~85us, VALU/LDS-bound, occupancy-exonerated).
// ROUND-9: no __threadfence in L2-dependent kernels. ROUND-4: no forced
// min-waves launch_bounds. ROUND-6/8: audit overlay lifetimes vs schedule.
// B=2 S=2048 H=2048 nh=16 hd=128 rd=64 L=256
// ---------------------------------------------------------------------------

typedef __attribute__((ext_vector_type(8))) short bf16x8;
typedef __attribute__((ext_vector_type(4))) float f32x4;
typedef unsigned int u32;

#define MFMA16(a, b, c) __builtin_amdgcn_mfma_f32_16x16x32_bf16(a, b, c, 0, 0, 0)

#define QSCALE_F (0.08838834764831845f * 1.4426950408889634f)
#define ROPE_EXP (-0.2878231366242557f)

__device__ __forceinline__ short f2bs(float f) {
  __hip_bfloat16 h = __float2bfloat16(f);
  return *reinterpret_cast<short*>(&h);
}
__device__ __forceinline__ float bs2f(short s) {
  union { unsigned int u; float f; } v;
  v.u = ((unsigned int)(unsigned short)s) << 16;
  return v.f;
}
__device__ __forceinline__ u32 fbits(float f) {
  union { float f; u32 u; } v; v.f = f; return v.u;
}

__device__ __forceinline__ void async16(const void* g, void* l) {
  __builtin_amdgcn_global_load_lds(
      (const __attribute__((address_space(1))) u32*)(unsigned long long)g,
      (__attribute__((address_space(3))) u32*)(unsigned int)(unsigned long long)l,
      16, 0, 0);
}
__device__ __forceinline__ void wait_vm0() {
  __builtin_amdgcn_s_waitcnt(0x0f70);  // vmcnt(0) only
}

// XCD-aware block remap: co-locate same-row-panel blocks on one XCD.
// Bijective for gridDim.y % 8 == 0 (ny=32 for all our GEMM grids).
__device__ __forceinline__ void xcd_remap(int& bx, int& by) {
  const int id = blockIdx.y * gridDim.x + blockIdx.x;
  const int nyp = gridDim.y >> 3;
  const int xcd = id & 7, t = id >> 3;
  by = xcd * nyp + (t % nyp);
  bx = t / nyp;
}

// ---------------- fused prep: cast hs + all weight transposes --------------
__device__ __forceinline__ void wtrans_tile(const float* __restrict__ W,
                                            short* __restrict__ Wt, int K, int N,
                                            int bx, int by, int tid) {
  __shared__ float t[32][33];
  int k0 = by * 32, n0 = bx * 32;
#pragma unroll
  for (int i = 0; i < 4; ++i) {
    int idx = tid + i * 256;
    int r = idx >> 5, c = idx & 31;
    t[r][c] = W[(size_t)(k0 + r) * N + n0 + c];
  }
  __syncthreads();
#pragma unroll
  for (int i = 0; i < 4; ++i) {
    int idx = tid + i * 256;
    int r = idx >> 5, c = idx & 31;
    Wt[(size_t)(n0 + r) * K + k0 + c] = f2bs(t[c][r]);
  }
}

__global__ __launch_bounds__(256) void prep_all(
    const float* __restrict__ hs, const float* __restrict__ Wkvd,
    const float* __restrict__ Wqd, const float* __restrict__ Wku,
    const float* __restrict__ Wqu, const float* __restrict__ Wvu,
    const float* __restrict__ Wrk, const float* __restrict__ Wrq,
    const float* __restrict__ Wo, short* __restrict__ hs_b,
    short* __restrict__ W1t, short* __restrict__ W2t,
    short* __restrict__ W3t, short* __restrict__ Wo_t) {
  const int b = blockIdx.x, tid = threadIdx.x;
  if (b < 8192) {
    int i = (b * 256 + tid) * 4;
    float4 v = *(const float4*)(hs + i);
    short4 o;
    o.x = f2bs(v.x); o.y = f2bs(v.y); o.z = f2bs(v.z); o.w = f2bs(v.w);
    *(short4*)(hs_b + i) = o;
  } else if (b < 8704) {
    int l = b - 8192; wtrans_tile(Wkvd, W1t, 2048, 256, l & 7, l >> 3, tid);
  } else if (b < 9216) {
    int l = b - 8704; wtrans_tile(Wqd, W1t + 256 * 2048, 2048, 256, l & 7, l >> 3, tid);
  } else if (b < 11264) {
    int l = b - 9216; wtrans_tile(Wrk, W1t + 512 * 2048, 2048, 1024, l & 31, l >> 5, tid);
  } else if (b < 11520) {
    int l = b - 11264; wtrans_tile(Wku, W2t, 256, 1024, l & 31, l >> 5, tid);
  } else if (b < 12032) {
    int l = b - 11520; wtrans_tile(Wvu, W2t + 1024 * 256, 256, 2048, l & 63, l >> 6, tid);
  } else if (b < 12288) {
    int l = b - 12032; wtrans_tile(Wqu, W3t, 256, 1024, l & 31, l >> 5, tid);
  } else if (b < 12544) {
    int l = b - 12288; wtrans_tile(Wrq, W3t + 1024 * 256, 256, 1024, l & 31, l >> 5, tid);
  } else {
    int l = b - 12544; wtrans_tile(Wo, Wo_t, 2048, 2048, l & 63, l >> 6, tid);
  }
}

// ---------------- bf16 MFMA GEMM, BK=64, double-buffered (Wo gemm) ---------
__device__ __forceinline__ void cstore(float v, float* p) { *p = v; }
__device__ __forceinline__ void cstore(float v, short* p) { *p = f2bs(v); }

template <typename CT>
__global__ __launch_bounds__(256) void gemm_bt(const short* __restrict__ A, int lda,
                                               const short* __restrict__ Bt, int ldb,
                                               CT* __restrict__ C, int ldc, int K) {
  __shared__ short As[2][128 * 64];
  __shared__ short Bs[2][128 * 64];
  const int tid = threadIdx.x;
  const int wave = tid >> 6, lane = tid & 63;
  const int quad = lane >> 4, l15 = lane & 15;
  const int wm = wave & 1, wn = wave >> 1;
  int bx, by; xcd_remap(bx, by);
  const int row0 = by * 128, col0 = bx * 128;
  const int sr = tid >> 3;
  const int sc = ((tid & 7) ^ (sr & 7)) * 8;
  const short* Ag = A + (size_t)(row0 + sr) * lda + sc;
  const short* Bg = Bt + (size_t)(col0 + sr) * ldb + sc;
  const int rk = l15 & 7;

  f32x4 acc[4][4];
#pragma unroll
  for (int i = 0; i < 4; ++i)
#pragma unroll
    for (int j = 0; j < 4; ++j) acc[i][j] = {0.f, 0.f, 0.f, 0.f};

  // prologue: stage k-step 0 into buf 0
#pragma unroll
  for (int i = 0; i < 4; ++i) {
    async16(Ag + (size_t)(i * 32) * lda, &As[0][i * 2048 + tid * 8]);
    async16(Bg + (size_t)(i * 32) * ldb, &Bs[0][i * 2048 + tid * 8]);
  }
  wait_vm0();
  __syncthreads();

  int cur = 0;
  for (int k0 = 0; k0 < K; k0 += 64) {
    if (k0 + 64 < K) {  // issue next k-step DMA into the other buffer
#pragma unroll
      for (int i = 0; i < 4; ++i) {
        async16(Ag + (size_t)(i * 32) * lda + k0 + 64, &As[cur ^ 1][i * 2048 + tid * 8]);
        async16(Bg + (size_t)(i * 32) * ldb + k0 + 64, &Bs[cur ^ 1][i * 2048 + tid * 8]);
      }
    }
    __builtin_amdgcn_s_setprio(1);
#pragma unroll
    for (int s = 0; s < 2; ++s) {
      bf16x8 af[4], bfr[4];
#pragma unroll
      for (int i = 0; i < 4; ++i) {
        af[i]  = *(const bf16x8*)&As[cur][(wm * 64 + i * 16 + l15) * 64 +
                                         ((s * 4 + quad) ^ rk) * 8];
        bfr[i] = *(const bf16x8*)&Bs[cur][(wn * 64 + i * 16 + l15) * 64 +
                                         ((s * 4 + quad) ^ rk) * 8];
      }
#pragma unroll
      for (int i = 0; i < 4; ++i)
#pragma unroll
        for (int j = 0; j < 4; ++j)
          acc[i][j] = MFMA16(af[i], bfr[j], acc[i][j]);
    }
    __builtin_amdgcn_s_setprio(0);
    wait_vm0();       // next k-step's DMA done (overlapped by compute)
    __syncthreads();  // all waves done reading cur + DMAs visible
    cur ^= 1;
  }
#pragma unroll
  for (int i = 0; i < 4; ++i)
#pragma unroll
    for (int j = 0; j < 4; ++j)
#pragma unroll
      for (int r = 0; r < 4; ++r) {
        int row = row0 + wm * 64 + i * 16 + quad * 4 + r;
        int col = col0 + wn * 64 + j * 16 + l15;
        cstore(acc[i][j][r], &C[(size_t)row * ldc + col]);
      }
}

// ---- gemm1k: C1[kvd|qd] + in-register RoPE for k_r -> k_f[64:] ------------
// (r13 epilogue verbatim; main loop double-buffered.)
__global__ __launch_bounds__(256) void gemm1k(const short* __restrict__ A,
                                              const short* __restrict__ Bt,
                                              short* __restrict__ C1,
                                              short* __restrict__ kf) {
  __shared__ short As[2][128 * 64];
  __shared__ short Bs[2][128 * 64];
  const int tid = threadIdx.x;
  const int wave = tid >> 6, lane = tid & 63;
  const int quad = lane >> 4, l15 = lane & 15;
  const int wm = wave & 1, wn = wave >> 1;
  int bx, by; xcd_remap(bx, by);
  const int row0 = by * 128, col0 = bx * 128;
  const int sr = tid >> 3;
  const int sc = ((tid & 7) ^ (sr & 7)) * 8;
  const short* Ag = A + (size_t)(row0 + sr) * 2048 + sc;
  const short* Bg = Bt + (size_t)(col0 + sr) * 2048 + sc;
  const int rk = l15 & 7;

  f32x4 acc[4][4];
#pragma unroll
  for (int i = 0; i < 4; ++i)
#pragma unroll
    for (int j = 0; j < 4; ++j) acc[i][j] = {0.f, 0.f, 0.f, 0.f};

#pragma unroll
  for (int i = 0; i < 4; ++i) {
    async16(Ag + (size_t)(i * 32) * 2048, &As[0][i * 2048 + tid * 8]);
    async16(Bg + (size_t)(i * 32) * 2048, &Bs[0][i * 2048 + tid * 8]);
  }
  wait_vm0();
  __syncthreads();

  int cur = 0;
  for (int k0 = 0; k0 < 2048; k0 += 64) {
    if (k0 + 64 < 2048) {
#pragma unroll
      for (int i = 0; i < 4; ++i) {
        async16(Ag + (size_t)(i * 32) * 2048 + k0 + 64, &As[cur ^ 1][i * 2048 + tid * 8]);
        async16(Bg + (size_t)(i * 32) * 2048 + k0 + 64, &Bs[cur ^ 1][i * 2048 + tid * 8]);
      }
    }
    __builtin_amdgcn_s_setprio(1);
#pragma unroll
    for (int s = 0; s < 2; ++s) {
      bf16x8 af[4], bfr[4];
#pragma unroll
      for (int i = 0; i < 4; ++i) {
        af[i]  = *(const bf16x8*)&As[cur][(wm * 64 + i * 16 + l15) * 64 +
                                         ((s * 4 + quad) ^ rk) * 8];
        bfr[i] = *(const bf16x8*)&Bs[cur][(wn * 64 + i * 16 + l15) * 64 +
                                         ((s * 4 + quad) ^ rk) * 8];
      }
#pragma unroll
      for (int i = 0; i < 4; ++i)
#pragma unroll
        for (int j = 0; j < 4; ++j)
          acc[i][j] = MFMA16(af[i], bfr[j], acc[i][j]);
    }
    __builtin_amdgcn_s_setprio(0);
    wait_vm0();
    __syncthreads();
    cur ^= 1;
  }

  if (bx < 4) {
#pragma unroll
    for (int i = 0; i < 4; ++i)
#pragma unroll
      for (int jj = 0; jj < 4; ++jj)
#pragma unroll
        for (int r = 0; r < 4; ++r) {
          int row = row0 + wm * 64 + i * 16 + quad * 4 + r;
          int col = col0 + wn * 64 + jj * 16 + l15;
          C1[(size_t)row * 512 + col] = f2bs(acc[i][jj][r]);
        }
  } else {
    const int colb = (bx - 4) * 128 + wn * 64 + l15;  // k_r col, jj=0
    const int h = colb >> 6;                          // constant over jj
    const float ef0 = __expf(ROPE_EXP * (float)l15);
    const float ef1 = __expf(ROPE_EXP * (float)(l15 + 16));
#pragma unroll
    for (int i = 0; i < 4; ++i)
#pragma unroll
      for (int r = 0; r < 4; ++r) {
        int row = row0 + wm * 64 + i * 16 + quad * 4 + r;
        int s = row & 2047, b = row >> 11;
        float fs = (float)s;
        float a0 = fs * ef0, a1 = fs * ef1;
        float c0 = __cosf(a0), s0 = __sinf(a0);
        float c1 = __cosf(a1), s1 = __sinf(a1);
        // jr<32: x*c - x_hi*s ; jr>=32: x*c + x_lo*s
        float o0 = acc[i][0][r] * c0 - acc[i][2][r] * s0;
        float o2 = acc[i][2][r] * c0 + acc[i][0][r] * s0;
        float o1 = acc[i][1][r] * c1 - acc[i][3][r] * s1;
        float o3 = acc[i][3][r] * c1 + acc[i][1][r] * s1;
        short* kp = kf + (((size_t)(b * 16 + h) * 2048 + s) * 128 + 64 + l15);
        kp[0]  = f2bs(o0);
        kp[16] = f2bs(o1);
        kp[32] = f2bs(o2);
        kp[48] = f2bs(o3);
      }
  }
}

// ---- gemm23: k_c->kf, v->vt, q_c->qf, q_r RoPE->qf ------------------------
// (r13 epilogues verbatim; main loop double-buffered.)
// REQUIRES: W3t == W2t + 3072*256 (enforced in kernel_launch layout).
__global__ __launch_bounds__(256) void gemm23(const short* __restrict__ C1,
                                              const short* __restrict__ W2t,
                                              short* __restrict__ qf,
                                              short* __restrict__ kf,
                                              short* __restrict__ vt) {
  __shared__ short As[2][128 * 64];
  __shared__ short Bs[2][128 * 64];
  const int tid = threadIdx.x;
  const int wave = tid >> 6, lane = tid & 63;
  const int quad = lane >> 4, l15 = lane & 15;
  const int wm = wave & 1, wn = wave >> 1;
  int bx, by; xcd_remap(bx, by);
  const short* A = bx < 24 ? C1 : C1 + 256;  // kv_d vs q_d columns
  const int row0 = by * 128;
  const int sr = tid >> 3;
  const int sc = ((tid & 7) ^ (sr & 7)) * 8;
  const short* Ag = A + (size_t)(row0 + sr) * 512 + sc;
  const short* Bg = W2t + (size_t)(bx * 128 + sr) * 256 + sc;  // W3t contiguous
  const int rk = l15 & 7;

  f32x4 acc[4][4];
#pragma unroll
  for (int i = 0; i < 4; ++i)
#pragma unroll
    for (int j = 0; j < 4; ++j) acc[i][j] = {0.f, 0.f, 0.f, 0.f};

#pragma unroll
  for (int i = 0; i < 4; ++i) {
    async16(Ag + (size_t)(i * 32) * 512, &As[0][i * 2048 + tid * 8]);
    async16(Bg + (size_t)(i * 32) * 256, &Bs[0][i * 2048 + tid * 8]);
  }
  wait_vm0();
  __syncthreads();

  int cur = 0;
  for (int k0 = 0; k0 < 256; k0 += 64) {
    if (k0 + 64 < 256) {
#pragma unroll
      for (int i = 0; i < 4; ++i) {
        async16(Ag + (size_t)(i * 32) * 512 + k0 + 64, &As[cur ^ 1][i * 2048 + tid * 8]);
        async16(Bg + (size_t)(i * 32) * 256 + k0 + 64, &Bs[cur ^ 1][i * 2048 + tid * 8]);
      }
    }
    __builtin_amdgcn_s_setprio(1);
#pragma unroll
    for (int s = 0; s < 2; ++s) {
      bf16x8 af[4], bfr[4];
#pragma unroll
      for (int i = 0; i < 4; ++i) {
        af[i]  = *(const bf16x8*)&As[cur][(wm * 64 + i * 16 + l15) * 64 +
                                         ((s * 4 + quad) ^ rk) * 8];
        bfr[i] = *(const bf16x8*)&Bs[cur][(wn * 64 + i * 16 + l15) * 64 +
                                         ((s * 4 + quad) ^ rk) * 8];
      }
#pragma unroll
      for (int i = 0; i < 4; ++i)
#pragma unroll
        for (int j = 0; j < 4; ++j)
          acc[i][j] = MFMA16(af[i], bfr[j], acc[i][j]);
    }
    __builtin_amdgcn_s_setprio(0);
    wait_vm0();
    __syncthreads();
    cur ^= 1;
  }

  if (bx < 8) {
    // k_c -> kf[..][j<64]. colb&63 == l15; h constant over jj.
    const int colb = bx * 128 + wn * 64 + l15;
    const int h = colb >> 6;
#pragma unroll
    for (int i = 0; i < 4; ++i)
#pragma unroll
      for (int r = 0; r < 4; ++r) {
        int row = row0 + wm * 64 + i * 16 + quad * 4 + r;
        int s = row & 2047, b = row >> 11;
        short* kp = kf + (((size_t)(b * 16 + h) * 2048 + s) * 128 + l15);
#pragma unroll
        for (int jj = 0; jj < 4; ++jj) kp[jj * 16] = f2bs(acc[i][jj][r]);
      }
  } else if (bx < 24) {
    // v -> v_t direct transposed store (r12-verified).
    const int b = row0 >> 11;
    const int s0 = row0 & 2047;
#pragma unroll
    for (int i = 0; i < 4; ++i)
#pragma unroll
      for (int jj = 0; jj < 4; ++jj) {
        int vcol = (bx - 8) * 128 + wn * 64 + jj * 16 + l15;  // 0..2047
        int h = vcol >> 7, d = vcol & 127;
        int s = s0 + wm * 64 + i * 16 + quad * 4;
        short4 o;
        o.x = f2bs(acc[i][jj][0]); o.y = f2bs(acc[i][jj][1]);
        o.z = f2bs(acc[i][jj][2]); o.w = f2bs(acc[i][jj][3]);
        *(short4*)&vt[((size_t)((b * 16 + h) * 128 + d)) * 2048 + s] = o;
      }
  } else if (bx < 32) {
    // q_c * QSCALE -> qf[..][j<64].
    const int colb = (bx - 24) * 128 + wn * 64 + l15;
    const int h = colb >> 6;
#pragma unroll
    for (int i = 0; i < 4; ++i)
#pragma unroll
      for (int r = 0; r < 4; ++r) {
        int row = row0 + wm * 64 + i * 16 + quad * 4 + r;
        int s = row & 2047, b = row >> 11;
        short* qp = qf + (((size_t)(b * 16 + h) * 2048 + s) * 128 + l15);
#pragma unroll
        for (int jj = 0; jj < 4; ++jj) qp[jj * 16] = f2bs(acc[i][jj][r] * QSCALE_F);
      }
  } else {
    // q_r RoPE * QSCALE -> qf[..][64+jr].
    const int colb = (bx - 32) * 128 + wn * 64 + l15;
    const int h = colb >> 6;
    const float ef0 = __expf(ROPE_EXP * (float)l15);
    const float ef1 = __expf(ROPE_EXP * (float)(l15 + 16));
#pragma unroll
    for (int i = 0; i < 4; ++i)
#pragma unroll
      for (int r = 0; r < 4; ++r) {
        int row = row0 + wm * 64 + i * 16 + quad * 4 + r;
        int s = row & 2047, b = row >> 11;
        float fs = (float)s;
        float a0 = fs * ef0, a1 = fs * ef1;
        float c0 = __cosf(a0), s0 = __sinf(a0);
        float c1 = __cosf(a1), s1 = __sinf(a1);
        float o0 = (acc[i][0][r] * c0 - acc[i][2][r] * s0) * QSCALE_F;
        float o2 = (acc[i][2][r] * c0 + acc[i][0][r] * s0) * QSCALE_F;
        float o1 = (acc[i][1][r] * c1 - acc[i][3][r] * s1) * QSCALE_F;
        float o3 = (acc[i][3][r] * c1 + acc[i][1][r] * s1) * QSCALE_F;
        short* qp = qf + (((size_t)(b * 16 + h) * 2048 + s) * 128 + 64 + l15);
        qp[0]  = f2bs(o0);
        qp[16] = f2bs(o1);
        qp[32] = f2bs(o2);
        qp[48] = f2bs(o3);
      }
  }
}

// ---------------- 2-way split-K flash attention, QBLK=64 KVBLK=32 ----------
// (r12 verbatim — parked at ~85us; occupancy-exonerated in r11.)
__global__ __launch_bounds__(256) void attn_split(const short* __restrict__ qf,
                                                  const short* __restrict__ kf,
                                                  const short* __restrict__ vt,
                                                  short* __restrict__ part,
                                                  float2* __restrict__ ml) {
  __shared__ short Ks[2][32 * 128];  // [kpos][d], granule-swizzled (16KB)
  __shared__ short Vs[2][128 * 32];  // [d][kpos], granule-swizzled (16KB)
  __shared__ short Pw[4][16 * 32];   // per-wave P^T, 2-bit XOR swz (4KB)
  const int lid = blockIdx.x;
  const int bh = (lid & 7) * 4 + ((lid >> 3) & 3);  // 4 bh per XCD
  const int x  = lid >> 5;                          // 0..31
  const int tid = threadIdx.x;
  const int wave = tid >> 6, lane = tid & 63;
  const int quad = lane >> 4, l15 = lane & 15;
  const int krow_l = tid >> 4;                      // 0..15
  const int kcol_sw = ((tid & 15) ^ krow_l) * 8;
  const int vrow_l = tid >> 2;                      // 0..63
  const int vcol_sw = ((tid & 3) ^ (vrow_l & 3) ^ ((vrow_l >> 2) & 3)) * 8;
  const short* kgB = kf + (((size_t)bh * 2048) + krow_l) * 128 + kcol_sw;
  const short* vgB = vt + ((size_t)bh * 128 + vrow_l) * 2048 + vcol_sw;
  const int pswz = l15 & 6;  // XOR on 4-short granule index bits 1..2

  for (int pass = 0; pass < 2; ++pass) {
    const int qt = pass ? 31 - x : x;       // 64-row q-tile index 0..31
    const int ks = pass ? qt + 1 : 0;       // half0 / half1 of causal range
    const int ke = pass ? 2 * (qt + 1) : x + 1;
    const int q0w = qt * 64 + wave * 16;

    bf16x8 qfr[4];
    {
      const short* qp = qf + (((size_t)bh * 2048) + q0w + l15) * 128;
#pragma unroll
      for (int kc = 0; kc < 4; ++kc)
        qfr[kc] = *(const bf16x8*)(qp + kc * 32 + quad * 8);
    }
    float m_i = -INFINITY;
    float l_i = 0.f;  // per-lane partial sum (reduced at pass end)
    f32x4 O[8];
#pragma unroll
    for (int dt = 0; dt < 8; ++dt) O[dt] = {0.f, 0.f, 0.f, 0.f};

    // prologue: stage first tile into buf 0 (2 async16 each per thread)
    {
      const short* kg = kgB + (size_t)ks * 32 * 128;
      const short* vg = vgB + ks * 32;
#pragma unroll
      for (int i = 0; i < 2; ++i) {
        async16(kg + (size_t)i * 16 * 128, &Ks[0][i * 2048 + tid * 8]);
        async16(vg + (size_t)i * 64 * 2048, &Vs[0][i * 2048 + tid * 8]);
      }
    }
    wait_vm0();
    __syncthreads();

    int cur = 0;
    for (int kt = ks; kt < ke; ++kt) {
      const int k0 = kt * 32;
      if (kt + 1 < ke) {  // DMA next tile into the other buffer (no barrier)
        const short* kg = kgB + (size_t)(kt + 1) * 32 * 128;
        const short* vg = vgB + (kt + 1) * 32;
#pragma unroll
        for (int i = 0; i < 2; ++i) {
          async16(kg + (size_t)i * 16 * 128, &Ks[cur ^ 1][i * 2048 + tid * 8]);
          async16(vg + (size_t)i * 64 * 2048, &Vs[cur ^ 1][i * 2048 + tid * 8]);
        }
      }

      // S^T = K @ Q^T  (m=kpos 32, n=qrow 16); lane col l15 = q-row
      f32x4 St[2];
#pragma unroll
      for (int j = 0; j < 2; ++j) St[j] = {0.f, 0.f, 0.f, 0.f};
      __builtin_amdgcn_s_setprio(1);
#pragma unroll
      for (int kc = 0; kc < 4; ++kc) {
        bf16x8 kb[2];
#pragma unroll
        for (int j = 0; j < 2; ++j)
          kb[j] = *(const bf16x8*)&Ks[cur][(j * 16 + l15) * 128 +
                                          (((kc * 4 + quad) ^ l15) & 15) * 8];
#pragma unroll
        for (int j = 0; j < 2; ++j)
          St[j] = MFMA16(kb[j], qfr[kc], St[j]);
      }
      __builtin_amdgcn_s_setprio(0);

      if (kt >= 2 * qt) {  // diagonal: causal mask
#pragma unroll
        for (int j = 0; j < 2; ++j)
#pragma unroll
          for (int r = 0; r < 4; ++r)
            if (k0 + j * 16 + quad * 4 + r > q0w + l15)
              St[j][r] = -INFINITY;
      }

      // online softmax: defer-max, per-lane trigger, per-lane partial l
      {
        float mt = -INFINITY;  // per-lane local max over 8 vals
#pragma unroll
        for (int j = 0; j < 2; ++j)
#pragma unroll
          for (int r = 0; r < 4; ++r) mt = fmaxf(mt, St[j][r]);
        if (!__all(mt <= m_i + 8.f)) {
          mt = fmaxf(mt, __shfl_xor(mt, 16));
          mt = fmaxf(mt, __shfl_xor(mt, 32));
          float mnew = fmaxf(m_i, mt);  // finite: trigger implies finite mt
          float a = __builtin_amdgcn_exp2f(m_i - mnew);  // -inf -> 0
          m_i = mnew;
          l_i *= a;
#pragma unroll
          for (int dt = 0; dt < 8; ++dt)
#pragma unroll
            for (int r = 0; r < 4; ++r) O[dt][r] *= a;
        }
        float ms = (m_i == -INFINITY) ? 0.f : m_i;
        float ps = 0.f;
#pragma unroll
        for (int j = 0; j < 2; ++j)
#pragma unroll
          for (int r = 0; r < 4; ++r) {
            float p = __builtin_amdgcn_exp2f(St[j][r] - ms);
            St[j][r] = p;
            ps += p;
          }
        l_i += ps;
      }

      // P^T (truncated bf16) -> per-wave LDS, 32 shorts/row, granule-XOR swz
      {
        int pr = l15;
#pragma unroll
        for (int j = 0; j < 2; ++j) {
          u32 u0 = (fbits(St[j][1]) & 0xffff0000u) | (fbits(St[j][0]) >> 16);
          u32 u1 = (fbits(St[j][3]) & 0xffff0000u) | (fbits(St[j][2]) >> 16);
          uint2 pk; pk.x = u0; pk.y = u1;
          int g = (j * 4 + quad) ^ pswz;  // logical granule j*4+quad
          *(uint2*)&Pw[wave][pr * 32 + g * 4] = pk;
        }
      }

      // O^T += V^T-frag @ P-frag (K=32: single k-chunk)
      __builtin_amdgcn_s_setprio(1);
      bf16x8 pa;
      {
        int g = (quad * 2) ^ pswz;  // logical granules 2q,2q+1 (pswz even)
        pa = *(const bf16x8*)&Pw[wave][l15 * 32 + g * 4];
      }
#pragma unroll
      for (int dt = 0; dt < 8; ++dt) {
        bf16x8 vb = *(const bf16x8*)&Vs[cur][(dt * 16 + l15) * 32 +
                                            ((quad ^ (l15 & 3) ^ ((l15 >> 2) & 3)) & 3) * 8];
        O[dt] = MFMA16(vb, pa, O[dt]);
      }
      __builtin_amdgcn_s_setprio(0);

      wait_vm0();       // next tile's DMA done (overlapped by compute above)
      __syncthreads();  // all waves done reading cur + all DMAs drained
      cur ^= 1;
    }

    // store partial O as bf16: [qrow 64][d 128]
    const int pidx = (bh * 32 + qt) * 2 + pass;
    short* pb = part + (size_t)pidx * 64 * 128;
    {
      int qrow = wave * 16 + l15;
#pragma unroll
      for (int dt = 0; dt < 8; ++dt) {
        short4 o;
        o.x = f2bs(O[dt][0]); o.y = f2bs(O[dt][1]);
        o.z = f2bs(O[dt][2]); o.w = f2bs(O[dt][3]);
        *(short4*)&pb[(size_t)qrow * 128 + dt * 16 + quad * 4] = o;
      }
    }
    // cross-quad reduce of per-lane l partials (all lanes execute shfls)
    float lr = l_i;
    lr += __shfl_xor(lr, 16);
    lr += __shfl_xor(lr, 32);
    if (quad == 0) {
      float2 v; v.x = m_i; v.y = lr;
      ml[pidx * 64 + wave * 16 + l15] = v;
    }
  }
}

// ---------------- merge two partials per 64-row q-tile ---------------------
// grid 1024, XCD-matched decode (lid%8 == bh>>2).
__global__ __launch_bounds__(256) void attn_merge(const short* __restrict__ part,
                                                  const float2* __restrict__ ml,
                                                  short* __restrict__ y) {
  const int l = blockIdx.x;
  const int bh = ((l & 7) << 2) | ((l >> 3) & 3);
  const int qt = (l >> 5) & 31;
  const int b = bh >> 4, h = bh & 15;
  const int row = threadIdx.x >> 2, d0 = (threadIdx.x & 3) * 32;
  const int p1 = (bh * 32 + qt) * 2, p2 = p1 + 1;
  float2 a = ml[p1 * 64 + row], c = ml[p2 * 64 + row];
  float m = fmaxf(a.x, c.x);
  float a1 = __builtin_amdgcn_exp2f(a.x - m);
  float a2 = __builtin_amdgcn_exp2f(c.x - m);
  float invl = 1.f / (a.y * a1 + c.y * a2);
  a1 *= invl; a2 *= invl;
  const short* s1 = part + ((size_t)p1 * 64 + row) * 128 + d0;
  const short* s2 = part + ((size_t)p2 * 64 + row) * 128 + d0;
  short* yp = y + (((size_t)b * 2048 + qt * 64 + row) * 16 + h) * 128 + d0;
#pragma unroll
  for (int j = 0; j < 8; ++j) {
    short4 v1 = *(const short4*)(s1 + j * 4);
    short4 v2 = *(const short4*)(s2 + j * 4);
    short4 o;
    o.x = f2bs(bs2f(v1.x) * a1 + bs2f(v2.x) * a2);
    o.y = f2bs(bs2f(v1.y) * a1 + bs2f(v2.y) * a2);
    o.z = f2bs(bs2f(v1.z) * a1 + bs2f(v2.z) * a2);
    o.w = f2bs(bs2f(v1.w) * a1 + bs2f(v2.w) * a2);
    *(short4*)(yp + j * 4) = o;
  }
}

extern "C" void kernel_launch(void* const* d_in, const int* in_sizes, int n_in,
                              void* d_out, int out_size, void* d_ws, size_t ws_size,
                              hipStream_t stream) {
  const float* hs   = (const float*)d_in[0];
  const float* Wkvd = (const float*)d_in[1];
  const float* Wqd  = (const float*)d_in[2];
  const float* Wku  = (const float*)d_in[3];
  const float* Wqu  = (const float*)d_in[4];
  const float* Wvu  = (const float*)d_in[5];
  const float* Wrk  = (const float*)d_in[6];
  const float* Wrq  = (const float*)d_in[7];
  const float* Wo   = (const float*)d_in[8];
  float* out = (float*)d_out;
  char* ws = (char*)d_ws;
  const size_t MB = 1024ull * 1024ull;

  short* hs_b = (short*)(ws + 0 * MB);     // 16 MB
  short* W1t  = (short*)(ws + 16 * MB);    // (1536,2048): kvd|qd|rk ^T
  short* W2t  = (short*)(ws + 22 * MB);    // (3072,256): ku|vu ^T
  short* W3t  = W2t + 3072 * 256;          // (2048,256): qu|rq ^T — CONTIGUOUS
                                           //  after W2t (gemm23 requires it)
  short* C1   = (short*)(ws + 25 * MB);    // (4096,512): kv_d|q_d (4 MB)
  short* Wo_t = (short*)(ws + 77 * MB);    // (2048,2048)
  short* q_f  = (short*)(ws + 85 * MB);    // (32,2048,128)
  short* k_f  = (short*)(ws + 101 * MB);   // j<64 by gemm23, j>=64 by gemm1k
  short* v_t  = (short*)(ws + 117 * MB);   // (32,128,2048) — by gemm23
  short* y_b  = (short*)(ws + 133 * MB);   // (b,s,h,d)
  short*  partb = (short*)(ws + 0 * MB);   // overlay: 2048x64x128 bf16 (32 MB)
  float2* mlb   = (float2*)(ws + 32 * MB); // 1 MB (dead region at attn time)

  dim3 blk(256);
  prep_all<<<dim3(16640), blk, 0, stream>>>(hs, Wkvd, Wqd, Wku, Wqu, Wvu, Wrk,
                                            Wrq, Wo, hs_b, W1t, W2t, W3t, Wo_t);

  gemm1k<<<dim3(12, 32), blk, 0, stream>>>(hs_b, W1t, C1, k_f);
  gemm23<<<dim3(40, 32), blk, 0, stream>>>(C1, W2t, q_f, k_f, v_t);

  attn_split<<<dim3(1024), blk, 0, stream>>>(q_f, k_f, v_t, partb, mlb);
  attn_merge<<<dim3(1024), blk, 0, stream>>>(partb, mlb, y_b);

  gemm_bt<float><<<dim3(16, 32), blk, 0, stream>>>(y_b, 2048, Wo_t, 2048, out, 2048, 2048);
}